// Round 5
// baseline (304.916 us; speedup 1.0000x reference)
//
#include <hip/hip_runtime.h>

#define US unsigned short

typedef __bf16 bf16x8 __attribute__((ext_vector_type(8)));
typedef float f32x4 __attribute__((ext_vector_type(4)));
typedef unsigned int u32x4 __attribute__((ext_vector_type(4)));
typedef unsigned short u16x4 __attribute__((ext_vector_type(4)));
typedef unsigned int uint2v __attribute__((ext_vector_type(2)));

// 0.125 (softmax 1/sqrt(D)) * log2(e): folded into W'q and b'q -> P = exp2(s).
#define ALPHA_Q 0.180336880111f

#if __has_builtin(__builtin_amdgcn_exp2f)
#define EXP2F(x) __builtin_amdgcn_exp2f(x)
#else
#define EXP2F(x) __expf(0.69314718f * (x))
#endif

static __device__ __forceinline__ US f2bf(float f) {  // RTNE
    union { float f; unsigned u; } v; v.f = f;
    unsigned r = v.u + 0x7fffu + ((v.u >> 16) & 1u);
    return (US)(r >> 16);
}
static __device__ __forceinline__ unsigned bftr(float f) {  // trunc to bf16 bits
    union { float f; unsigned u; } v; v.f = f;
    return v.u >> 16;
}
static __device__ __forceinline__ float bf2f(US h) {
    union { unsigned u; float f; } v; v.u = ((unsigned)h) << 16;
    return v.f;
}
static __device__ __forceinline__ f32x4 mfma16(bf16x8 a, bf16x8 b, f32x4 c) {
    return __builtin_amdgcn_mfma_f32_16x16x32_bf16(a, b, c, 0, 0, 0);
}
// async global->LDS, 16B/lane; LDS dest = base + lane*16 (wave-uniform base)
static __device__ __forceinline__ void gload16(const US* g, US* l) {
    __builtin_amdgcn_global_load_lds(
        (const __attribute__((address_space(1))) void*)g,
        (__attribute__((address_space(3))) void*)l, 16, 0, 0);
}
static __device__ __forceinline__ void stf(float* p, float v) { *p = v; }
static __device__ __forceinline__ void stf(US* p, float v) { *p = f2bf(v); }

// ---------------------------------------------------------------------------
// Fused prep (one launch): [0,6144) f32->bf16 casts; [6144,7168) 4 transposes
// (Rm->rt, Em->et, Wq->wqT, Wk->wkT); [7168,7216) fused-bias blocks.
// ---------------------------------------------------------------------------
__global__ __launch_bounds__(256) void prep(
    const float* __restrict__ x, US* __restrict__ xb,
    const float* __restrict__ qkvw, US* __restrict__ wv,
    const float* __restrict__ outw, US* __restrict__ wo,
    const float* __restrict__ Rm, US* __restrict__ rt,
    const float* __restrict__ Em, US* __restrict__ et,
    US* __restrict__ wqT, US* __restrict__ wkT,
    const float* __restrict__ qkvb, float* __restrict__ b3)
{
    __shared__ float t[64][65];
    const int bx = blockIdx.x;
    if (bx < 6144) {            // bulk casts: x (4096 blks), Wv (1024), Wo (1024)
        int i = bx * 256 + threadIdx.x;
        const float* s; US* d; int j;
        if (i < 1048576) { s = x; d = xb; j = i; }
        else if (i < 1310720) { s = qkvw + (size_t)2048 * 1024; d = wv; j = i - 1048576; }
        else { s = outw; d = wo; j = i - 1310720; }
        f32x4 v = ((const f32x4*)s)[j];
        u16x4 o;
        o.x = f2bf(v.x); o.y = f2bf(v.y); o.z = f2bf(v.z); o.w = f2bf(v.w);
        ((u16x4*)d)[j] = o;
    } else if (bx < 7168) {     // 4 x 1024x1024 fp32->bf16 transposes
        int r = bx - 6144;
        int z = r >> 8, xy = r & 255, tbx = xy & 15, tby = xy >> 4;
        const float* ip; US* op;
        switch (z) {
            case 0: ip = Rm; op = rt; break;
            case 1: ip = Em; op = et; break;
            case 2: ip = qkvw; op = wqT; break;
            default: ip = qkvw + (size_t)1024 * 1024; op = wkT; break;
        }
        int bc = tbx * 64, br = tby * 64;
        int lx = threadIdx.x & 63, y4 = threadIdx.x >> 6;
#pragma unroll
        for (int i = 0; i < 16; ++i) {
            int rr = i * 4 + y4;
            t[rr][lx] = ip[(size_t)(br + rr) * 1024 + bc + lx];
        }
        __syncthreads();
#pragma unroll
        for (int i = 0; i < 16; ++i) {
            int c = i * 4 + y4;
            op[(size_t)(bc + c) * 1024 + br + lx] = f2bf(t[lx][c]);
        }
    } else {                    // bias': b'q = (bq.R)*ALPHA_Q ; b'k = bk.E ; b'v
        float (*red)[64] = (float(*)[64])t;
        const int bb = bx - 7168;                 // 0..47
        const int tid = threadIdx.x, wave = tid >> 6, lane = tid & 63;
        const int n0 = bb * 64, n = n0 + lane;
        if (n0 >= 2048) {
            if (wave == 0) b3[n] = qkvb[n];
            return;
        }
        const float* M = (n0 < 1024) ? Rm : Em;
        const float* bv = qkvb + ((n0 < 1024) ? 0 : 1024);
        const int nn = (n0 < 1024) ? n : n - 1024;
        float s = 0.f;
        const int j0 = wave * 256;
#pragma unroll 8
        for (int j = 0; j < 256; ++j)
            s += bv[j0 + j] * M[(size_t)(j0 + j) * 1024 + nn];
        red[wave][lane] = s;
        __syncthreads();
        if (wave == 0) {
            float tt = red[0][lane] + red[1][lane] + red[2][lane] + red[3][lane];
            b3[n] = (n0 < 1024) ? tt * ALPHA_Q : tt;
        }
    }
}

// ---------------------------------------------------------------------------
// bf16 batched transpose (for V): out[c][r] = in[r][c].
// ---------------------------------------------------------------------------
__global__ __launch_bounds__(256) void transpose_bf(
    const US* __restrict__ in, US* __restrict__ out,
    int ldin, int ldout, long in_batch, long out_batch)
{
    __shared__ float t[64][65];
    const US* ip = in + (size_t)blockIdx.z * in_batch;
    US* op = out + (size_t)blockIdx.z * out_batch;
    int bc = blockIdx.x * 64, br = blockIdx.y * 64;
    int x = threadIdx.x & 63, y4 = threadIdx.x >> 6;
#pragma unroll
    for (int i = 0; i < 16; ++i) {
        int r = i * 4 + y4;
        t[r][x] = bf2f(ip[(size_t)(br + r) * ldin + bc + x]);
    }
    __syncthreads();
#pragma unroll
    for (int i = 0; i < 16; ++i) {
        int c = i * 4 + y4;
        op[(size_t)(bc + c) * ldout + br + x] = f2bf(t[x][c]);
    }
}

// ---------------------------------------------------------------------------
// NT GEMM 128x128 tile (m97-style): C = alpha*A.B^T (+bias) (+resid).
// ---------------------------------------------------------------------------
template <typename TO>
__global__ __launch_bounds__(256) void gemm_nt(
    const US* __restrict__ A, const US* __restrict__ Bm,
    TO* __restrict__ C, const float* __restrict__ bias,
    const float* __restrict__ resid, float alpha,
    int M, int N, int K, int lda, int ldb, int ldc)
{
    __shared__ __align__(16) US sA[128 * 32];
    __shared__ __align__(16) US sB[128 * 32];
    const int tid = threadIdx.x;
    const int wave = tid >> 6, lane = tid & 63;
    const int r16 = lane & 15, q4 = lane >> 4;
    const int wm = (wave >> 1) * 64, wn = (wave & 1) * 64;

    const int srow = wave * 32 + (lane >> 2);
    const int sg = lane & 3;
    const US* aptr = A + (size_t)(blockIdx.x * 128 + srow) * lda + sg * 8;
    const US* bptr = Bm + (size_t)(blockIdx.y * 128 + srow) * ldb + sg * 8;
    US* lA = sA + (wave * 32) * 32;
    US* lB = sB + (wave * 32) * 32;

    f32x4 acc[4][4];
#pragma unroll
    for (int i = 0; i < 4; ++i)
#pragma unroll
        for (int j = 0; j < 4; ++j) acc[i][j] = (f32x4){0.f, 0.f, 0.f, 0.f};

    for (int k0 = 0; k0 < K; k0 += 32) {
        gload16(aptr + k0, lA);
        gload16(aptr + (size_t)16 * lda + k0, lA + 16 * 32);
        gload16(bptr + k0, lB);
        gload16(bptr + (size_t)16 * ldb + k0, lB + 16 * 32);
        __syncthreads();
        bf16x8 af[4], bfr[4];
#pragma unroll
        for (int i = 0; i < 4; ++i)
            af[i] = *(const bf16x8*)&sA[(wm + i * 16 + r16) * 32 + q4 * 8];
#pragma unroll
        for (int j = 0; j < 4; ++j)
            bfr[j] = *(const bf16x8*)&sB[(wn + j * 16 + r16) * 32 + q4 * 8];
#pragma unroll
        for (int i = 0; i < 4; ++i)
#pragma unroll
            for (int j = 0; j < 4; ++j) acc[i][j] = mfma16(af[i], bfr[j], acc[i][j]);
        __syncthreads();
    }

#pragma unroll
    for (int j = 0; j < 4; ++j) {
        int col = blockIdx.y * 128 + wn + j * 16 + r16;
        float bv = bias ? bias[col] : 0.f;
#pragma unroll
        for (int i = 0; i < 4; ++i) {
#pragma unroll
            for (int rr = 0; rr < 4; ++rr) {
                int row = blockIdx.x * 128 + wm + i * 16 + q4 * 4 + rr;
                float v = acc[i][j][rr] * alpha + bv;
                if (resid) v += resid[(size_t)row * ldc + col];
                stf(&C[(size_t)row * ldc + col], v);
            }
        }
    }
}

// ---------------------------------------------------------------------------
// Weight-fold GEMMs, 64x64 tiles, both folds in one launch (z: 0=q, 1=k).
// ---------------------------------------------------------------------------
__global__ __launch_bounds__(256) void gemm_fold(
    const US* __restrict__ rt, const US* __restrict__ wqT,
    const US* __restrict__ et, const US* __restrict__ wkT,
    US* __restrict__ comb)
{
    __shared__ __align__(16) US sA[64 * 32];
    __shared__ __align__(16) US sB[64 * 32];
    const US* A; const US* Bm; US* C; float alpha;
    if (blockIdx.z == 0) { A = rt; Bm = wqT; C = comb; alpha = ALPHA_Q; }
    else { A = et; Bm = wkT; C = comb + (size_t)1024 * 1024; alpha = 1.0f; }

    const int tid = threadIdx.x;
    const int wave = tid >> 6, lane = tid & 63;
    const int r16 = lane & 15, q4 = lane >> 4;
    const int wm = (wave >> 1) * 32, wn = (wave & 1) * 32;

    const int srow = wave * 16 + (lane >> 2);
    const int sg = lane & 3;
    const US* aptr = A + (size_t)(blockIdx.x * 64 + srow) * 1024 + sg * 8;
    const US* bptr = Bm + (size_t)(blockIdx.y * 64 + srow) * 1024 + sg * 8;
    US* lA = sA + (wave * 16) * 32;
    US* lB = sB + (wave * 16) * 32;

    f32x4 acc[2][2];
#pragma unroll
    for (int i = 0; i < 2; ++i)
#pragma unroll
        for (int j = 0; j < 2; ++j) acc[i][j] = (f32x4){0.f, 0.f, 0.f, 0.f};

    for (int k0 = 0; k0 < 1024; k0 += 32) {
        gload16(aptr + k0, lA);
        gload16(bptr + k0, lB);
        __syncthreads();
        bf16x8 af[2], bfr[2];
#pragma unroll
        for (int i = 0; i < 2; ++i)
            af[i] = *(const bf16x8*)&sA[(wm + i * 16 + r16) * 32 + q4 * 8];
#pragma unroll
        for (int j = 0; j < 2; ++j)
            bfr[j] = *(const bf16x8*)&sB[(wn + j * 16 + r16) * 32 + q4 * 8];
#pragma unroll
        for (int i = 0; i < 2; ++i)
#pragma unroll
            for (int j = 0; j < 2; ++j) acc[i][j] = mfma16(af[i], bfr[j], acc[i][j]);
        __syncthreads();
    }

#pragma unroll
    for (int j = 0; j < 2; ++j) {
        int col = blockIdx.y * 64 + wn + j * 16 + r16;
#pragma unroll
        for (int i = 0; i < 2; ++i)
#pragma unroll
            for (int rr = 0; rr < 4; ++rr) {
                int row = blockIdx.x * 64 + wm + i * 16 + q4 * 4 + rr;
                C[(size_t)row * 1024 + col] = f2bf(acc[i][j][rr] * alpha);
            }
    }
}

// ---------------------------------------------------------------------------
// Flash attention, barrier-free. B=2 H=16 S=2048 D=64; scores pre-scaled
// (log2 domain). Each WAVE owns 64 q-rows of one (b,h) pair and streams all
// 2048 keys in 32-key tiles through wave-private double-buffered LDS
// (global_load_lds + vmcnt(8) gating — no __syncthreads anywhere).
// Transposed algebra: S^T = K.Q^T, O^T = V^T.P^T, so P round-trips LDS as
// packed b64 writes and l is one scalar per lane (2 shuffles at the end).
// Block = 2 waves x 64 q = 128 q-rows; grid 512; XCD swizzle for K/V L2 reuse.
// ---------------------------------------------------------------------------
__global__ __launch_bounds__(128) void attn_kernel(
    const US* __restrict__ qkvq, const US* __restrict__ vt, US* __restrict__ out)
{
    // per wave: K dbuf 2*2048 | V dbuf 2*2048 | P 64*40  (21504 B) x 2 waves
    __shared__ __align__(16) US lds[2][10752];
    const int tid = threadIdx.x;
    const int wave = tid >> 6, lane = tid & 63;
    const int r16 = lane & 15, q4 = lane >> 4;
    const int bid = blockIdx.x;                 // 512
    const int xcd = bid & 7, idx = bid >> 3;
    const int pair = xcd * 4 + (idx & 3);       // 4 (b,h) pairs per XCD
    const int qc = idx >> 2;                    // 0..15
    const int h = pair & 15, b = pair >> 4;
    const int qrow0 = qc * 128 + wave * 64;

    US* myK = lds[wave];                        // [buf][key32][d64], swizzled
    US* myV = myK + 4096;                       // [buf][d64][key32], swizzled
    US* myP = myV + 4096;                       // [q64][40]

    // Q B-frags: B[n=q][k=d]
    const US* qbase = qkvq + ((size_t)(b * 2048 + qrow0)) * 3072 + h * 64;
    bf16x8 qa[4][2];
#pragma unroll
    for (int qt = 0; qt < 4; ++qt)
#pragma unroll
        for (int kh = 0; kh < 2; ++kh)
            qa[qt][kh] = *(const bf16x8*)(qbase + (size_t)(qt * 16 + r16) * 3072 + kh * 32 + q4 * 8);

    f32x4 o[4][4];
#pragma unroll
    for (int dt = 0; dt < 4; ++dt)
#pragma unroll
        for (int qt = 0; qt < 4; ++qt) o[dt][qt] = (f32x4){0.f, 0.f, 0.f, 0.f};
    float lacc = 0.f;

    // staging lane constants
    const int sr8 = lane >> 3;                          // K: 8 rows/call (128B rows)
    const US* kg = qkvq + ((size_t)(b * 2048 + sr8)) * 3072 + 1024 + h * 64
                 + (((lane & 7) ^ sr8)) * 8;
    const int sr4 = lane >> 2;                          // V: 16 rows/call (64B rows)
    const US* vg = vt + ((size_t)(b * 16 + h)) * 64 * 2048 + (size_t)sr4 * 2048
                 + (((lane & 3) ^ (sr4 & 3))) * 8;

    const int swK = r16 & 7, swV = r16 & 3;

#define STAGE(kc, buf) do {                                                   \
        US* dK = myK + (buf) * 2048;                                          \
        US* dV = myV + (buf) * 2048;                                          \
        _Pragma("unroll")                                                     \
        for (int c = 0; c < 4; ++c)                                           \
            gload16(kg + (size_t)((kc) + 8 * c) * 3072, dK + c * 512);        \
        _Pragma("unroll")                                                     \
        for (int c = 0; c < 4; ++c)                                           \
            gload16(vg + (size_t)(16 * c) * 2048 + (kc), dV + c * 512);       \
    } while (0)

    STAGE(0, 0);
    for (int it = 0; it < 64; ++it) {
        const int buf = it & 1;
        STAGE(((it + 1) & 63) * 32, buf ^ 1);
        asm volatile("s_waitcnt vmcnt(8)" ::: "memory");  // current buf ready
        const US* K0 = myK + buf * 2048;
        const US* V0 = myV + buf * 2048;

        // S^T = K.Q^T : A=K-frag [m=key][k=d], B=Q-frag [n=q][k=d]
        f32x4 st[2][4];
#pragma unroll
        for (int kt = 0; kt < 2; ++kt) {
            bf16x8 kf0 = *(const bf16x8*)&K0[(kt * 16 + r16) * 64 + ((0 + q4) ^ swK) * 8];
            bf16x8 kf1 = *(const bf16x8*)&K0[(kt * 16 + r16) * 64 + ((4 + q4) ^ swK) * 8];
#pragma unroll
            for (int qt = 0; qt < 4; ++qt) {
                st[kt][qt] = mfma16(kf0, qa[qt][0], (f32x4){0.f, 0.f, 0.f, 0.f});
                st[kt][qt] = mfma16(kf1, qa[qt][1], st[kt][qt]);
            }
        }
        // P^T = exp2(S^T): lane owns q=r16, keys kt*16+q4*4+rr -> packed b64
#pragma unroll
        for (int qt = 0; qt < 4; ++qt)
#pragma unroll
            for (int kt = 0; kt < 2; ++kt) {
                float p0 = EXP2F(st[kt][qt][0]), p1 = EXP2F(st[kt][qt][1]);
                float p2 = EXP2F(st[kt][qt][2]), p3 = EXP2F(st[kt][qt][3]);
                lacc += (p0 + p1) + (p2 + p3);
                uint2v w;
                w.x = bftr(p0) | (bftr(p1) << 16);
                w.y = bftr(p2) | (bftr(p3) << 16);
                *(uint2v*)&myP[(qt * 16 + r16) * 40 + kt * 16 + q4 * 4] = w;
            }
        asm volatile("s_waitcnt lgkmcnt(0)" ::: "memory");  // wave-local P vis

        // O^T += V^T.P^T : A=V-frag [m=d][k=key], B=P-frag [n=q][k=key]
        bf16x8 pa[4];
#pragma unroll
        for (int qt = 0; qt < 4; ++qt)
            pa[qt] = *(const bf16x8*)&myP[(qt * 16 + r16) * 40 + q4 * 8];
#pragma unroll
        for (int dt = 0; dt < 4; ++dt) {
            bf16x8 vf = *(const bf16x8*)&V0[(dt * 16 + r16) * 32 + (q4 ^ swV) * 8];
#pragma unroll
            for (int qt = 0; qt < 4; ++qt)
                o[dt][qt] = mfma16(vf, pa[qt], o[dt][qt]);
        }
    }
#undef STAGE

    // epilogue: l is per-lane (q = r16); reduce across the 4 quad groups
    float l = lacc;
    l += __shfl_xor(l, 16);
    l += __shfl_xor(l, 32);
    const float inv = 1.0f / l;
#pragma unroll
    for (int qt = 0; qt < 4; ++qt) {
        const size_t row = (size_t)(b * 2048 + qrow0 + qt * 16 + r16);
#pragma unroll
        for (int dt = 0; dt < 4; ++dt) {
            uint2v w;
            w.x = (unsigned)f2bf(o[dt][qt][0] * inv) | ((unsigned)f2bf(o[dt][qt][1] * inv) << 16);
            w.y = (unsigned)f2bf(o[dt][qt][2] * inv) | ((unsigned)f2bf(o[dt][qt][3] * inv) << 16);
            *(uint2v*)&out[row * 1024 + h * 64 + dt * 16 + q4 * 4] = w;
        }
    }
}

// ---------------------------------------------------------------------------
// B=2, S=2048, E=1024, H=16, D=64. Inputs fp32, output fp32. 6 launches.
// ---------------------------------------------------------------------------
extern "C" void kernel_launch(void* const* d_in, const int* in_sizes, int n_in,
                              void* d_out, int out_size, void* d_ws, size_t ws_size,
                              hipStream_t stream)
{
    const float* x    = (const float*)d_in[0];
    const float* Rm   = (const float*)d_in[1];
    const float* Em   = (const float*)d_in[2];
    const float* qkvw = (const float*)d_in[3];
    const float* qkvb = (const float*)d_in[4];
    const float* outw = (const float*)d_in[5];
    const float* outb = (const float*)d_in[6];
    float* outp = (float*)d_out;

    US* ws    = (US*)d_ws;
    US* xb    = ws;
    US* rt    = xb   + (size_t)4096 * 1024;
    US* et    = rt   + (size_t)1024 * 1024;
    US* wqT   = et   + (size_t)1024 * 1024;
    US* wkT   = wqT  + (size_t)1024 * 1024;
    US* wo    = wkT  + (size_t)1024 * 1024;
    US* comb  = wo   + (size_t)1024 * 1024;   // 3072 x 1024 fused weight
    US* qkvq  = comb + (size_t)3072 * 1024;   // 4096 x 3072: q' | k' | v
    US* vt    = qkvq + (size_t)4096 * 3072;
    US* ao    = vt   + (size_t)4096 * 1024;
    float* b3 = (float*)(ao + (size_t)4096 * 1024);

    // casts + 4 transposes + fused-bias in one launch
    prep<<<dim3(7216), dim3(256), 0, stream>>>(
        x, xb, qkvw, comb + (size_t)2048 * 1024, outw, wo,
        Rm, rt, Em, et, wqT, wkT, qkvb, b3);
    // comb_q = ALPHA_Q * R^T Wq ; comb_k = E^T Wk
    gemm_fold<<<dim3(16, 16, 2), dim3(256), 0, stream>>>(rt, wqT, et, wkT, comb);
    // qkvq = x @ comb^T + b3  -> q' | k' | v
    gemm_nt<US><<<dim3(32, 24), dim3(256), 0, stream>>>(xb, comb, qkvq, b3, nullptr, 1.0f,
                                                        4096, 3072, 1024, 1024, 1024, 3072);
    // vt[b, d_feat, s] = v[b, s, d_feat]
    transpose_bf<<<dim3(16, 32, 2), dim3(256), 0, stream>>>(qkvq + 2048, vt, 3072, 2048,
                                                            (long)2048 * 3072, (long)1024 * 2048);
    // attention (barrier-free)
    attn_kernel<<<dim3(512), dim3(128), 0, stream>>>(qkvq, vt, ao);
    // out = ao @ out_w^T + out_b + x
    gemm_nt<float><<<dim3(32, 8), dim3(256), 0, stream>>>(ao, wo, outp, outb, x, 1.0f,
                                                          4096, 1024, 1024, 1024, 1024, 1024);
}

// Round 6
// 271.035 us; speedup vs baseline: 1.1250x; 1.1250x over previous
//
#include <hip/hip_runtime.h>

#define US unsigned short

typedef __bf16 bf16x8 __attribute__((ext_vector_type(8)));
typedef float f32x4 __attribute__((ext_vector_type(4)));
typedef unsigned int u32x4 __attribute__((ext_vector_type(4)));
typedef unsigned short u16x4 __attribute__((ext_vector_type(4)));
typedef unsigned int uint2v __attribute__((ext_vector_type(2)));

// 0.125 (softmax 1/sqrt(D)) * log2(e): folded into W'q and b'q -> P = exp2(s).
#define ALPHA_Q 0.180336880111f

#if __has_builtin(__builtin_amdgcn_exp2f)
#define EXP2F(x) __builtin_amdgcn_exp2f(x)
#else
#define EXP2F(x) __expf(0.69314718f * (x))
#endif

static __device__ __forceinline__ US f2bf(float f) {  // RTNE
    union { float f; unsigned u; } v; v.f = f;
    unsigned r = v.u + 0x7fffu + ((v.u >> 16) & 1u);
    return (US)(r >> 16);
}
static __device__ __forceinline__ unsigned bftr(float f) {  // trunc to bf16 bits
    union { float f; unsigned u; } v; v.f = f;
    return v.u >> 16;
}
static __device__ __forceinline__ float bf2f(US h) {
    union { unsigned u; float f; } v; v.u = ((unsigned)h) << 16;
    return v.f;
}
static __device__ __forceinline__ f32x4 mfma16(bf16x8 a, bf16x8 b, f32x4 c) {
    return __builtin_amdgcn_mfma_f32_16x16x32_bf16(a, b, c, 0, 0, 0);
}
// async global->LDS, 16B/lane; LDS dest = base + lane*16 (wave-uniform base)
static __device__ __forceinline__ void gload16(const US* g, US* l) {
    __builtin_amdgcn_global_load_lds(
        (const __attribute__((address_space(1))) void*)g,
        (__attribute__((address_space(3))) void*)l, 16, 0, 0);
}
static __device__ __forceinline__ void stf(float* p, float v) { *p = v; }
static __device__ __forceinline__ void stf(US* p, float v) { *p = f2bf(v); }

// ---------------------------------------------------------------------------
// Fused prep: [0,6144) f32->bf16 casts; [6144,7168) 4 transposes;
// [7168,7296) bias-GEMV partials (atomicAdd into pre-zeroed b3);
// [7296,7300) v-bias copy.
// ---------------------------------------------------------------------------
__global__ __launch_bounds__(256) void prep(
    const float* __restrict__ x, US* __restrict__ xb,
    const float* __restrict__ qkvw, US* __restrict__ wv,
    const float* __restrict__ outw, US* __restrict__ wo,
    const float* __restrict__ Rm, US* __restrict__ rt,
    const float* __restrict__ Em, US* __restrict__ et,
    US* __restrict__ wqT, US* __restrict__ wkT,
    const float* __restrict__ qkvb, float* __restrict__ b3)
{
    __shared__ float t[64][65];
    const int bx = blockIdx.x;
    if (bx < 6144) {            // bulk casts: x (4096 blks), Wv (1024), Wo (1024)
        int i = bx * 256 + threadIdx.x;
        const float* s; US* d; int j;
        if (i < 1048576) { s = x; d = xb; j = i; }
        else if (i < 1310720) { s = qkvw + (size_t)2048 * 1024; d = wv; j = i - 1048576; }
        else { s = outw; d = wo; j = i - 1310720; }
        f32x4 v = ((const f32x4*)s)[j];
        u16x4 o;
        o.x = f2bf(v.x); o.y = f2bf(v.y); o.z = f2bf(v.z); o.w = f2bf(v.w);
        ((u16x4*)d)[j] = o;
    } else if (bx < 7168) {     // 4 x 1024x1024 fp32->bf16 transposes
        int r = bx - 6144;
        int z = r >> 8, xy = r & 255, tbx = xy & 15, tby = xy >> 4;
        const float* ip; US* op;
        switch (z) {
            case 0: ip = Rm; op = rt; break;
            case 1: ip = Em; op = et; break;
            case 2: ip = qkvw; op = wqT; break;
            default: ip = qkvw + (size_t)1024 * 1024; op = wkT; break;
        }
        int bc = tbx * 64, br = tby * 64;
        int lx = threadIdx.x & 63, y4 = threadIdx.x >> 6;
#pragma unroll
        for (int i = 0; i < 16; ++i) {
            int rr = i * 4 + y4;
            t[rr][lx] = ip[(size_t)(br + rr) * 1024 + bc + lx];
        }
        __syncthreads();
#pragma unroll
        for (int i = 0; i < 16; ++i) {
            int c = i * 4 + y4;
            op[(size_t)(bc + c) * 1024 + br + lx] = f2bf(t[lx][c]);
        }
    } else if (bx < 7296) {     // bias GEMV partials: 32 n-chunks x 4 j-chunks
        float (*red)[64] = (float(*)[64])t;
        const int bb = bx - 7168;
        const int tid = threadIdx.x, wave = tid >> 6, lane = tid & 63;
        const int nc = bb & 31, jc = bb >> 5;
        const int n0 = nc * 64, n = n0 + lane;
        const float* M = (n0 < 1024) ? Rm : Em;
        const float* bv = qkvb + ((n0 < 1024) ? 0 : 1024);
        const int nn = (n0 < 1024) ? n : n - 1024;
        float s = 0.f;
        const int j0 = jc * 256 + wave * 64;
#pragma unroll 8
        for (int j = 0; j < 64; ++j)
            s += bv[j0 + j] * M[(size_t)(j0 + j) * 1024 + nn];
        red[wave][lane] = s;
        __syncthreads();
        if (wave == 0) {
            float tt = red[0][lane] + red[1][lane] + red[2][lane] + red[3][lane];
            atomicAdd(&b3[n], (n0 < 1024) ? tt * ALPHA_Q : tt);
        }
    } else {                    // v-bias copy (4 blocks x 256)
        int i = (bx - 7296) * 256 + threadIdx.x;
        b3[2048 + i] = qkvb[2048 + i];
    }
}

// ---------------------------------------------------------------------------
// bf16 batched transpose (for V): out[c][r] = in[r][c].
// ---------------------------------------------------------------------------
__global__ __launch_bounds__(256) void transpose_bf(
    const US* __restrict__ in, US* __restrict__ out,
    int ldin, int ldout, long in_batch, long out_batch)
{
    __shared__ float t[64][65];
    const US* ip = in + (size_t)blockIdx.z * in_batch;
    US* op = out + (size_t)blockIdx.z * out_batch;
    int bc = blockIdx.x * 64, br = blockIdx.y * 64;
    int x = threadIdx.x & 63, y4 = threadIdx.x >> 6;
#pragma unroll
    for (int i = 0; i < 16; ++i) {
        int r = i * 4 + y4;
        t[r][x] = bf2f(ip[(size_t)(br + r) * ldin + bc + x]);
    }
    __syncthreads();
#pragma unroll
    for (int i = 0; i < 16; ++i) {
        int c = i * 4 + y4;
        op[(size_t)(bc + c) * ldout + br + x] = f2bf(t[x][c]);
    }
}

// ---------------------------------------------------------------------------
// NT GEMM 128x128 tile (m97-style): C = alpha*A.B^T (+bias) (+resid).
// ---------------------------------------------------------------------------
template <typename TO>
__global__ __launch_bounds__(256) void gemm_nt(
    const US* __restrict__ A, const US* __restrict__ Bm,
    TO* __restrict__ C, const float* __restrict__ bias,
    const float* __restrict__ resid, float alpha,
    int M, int N, int K, int lda, int ldb, int ldc)
{
    __shared__ __align__(16) US sA[128 * 32];
    __shared__ __align__(16) US sB[128 * 32];
    const int tid = threadIdx.x;
    const int wave = tid >> 6, lane = tid & 63;
    const int r16 = lane & 15, q4 = lane >> 4;
    const int wm = (wave >> 1) * 64, wn = (wave & 1) * 64;

    const int srow = wave * 32 + (lane >> 2);
    const int sg = lane & 3;
    const US* aptr = A + (size_t)(blockIdx.x * 128 + srow) * lda + sg * 8;
    const US* bptr = Bm + (size_t)(blockIdx.y * 128 + srow) * ldb + sg * 8;
    US* lA = sA + (wave * 32) * 32;
    US* lB = sB + (wave * 32) * 32;

    f32x4 acc[4][4];
#pragma unroll
    for (int i = 0; i < 4; ++i)
#pragma unroll
        for (int j = 0; j < 4; ++j) acc[i][j] = (f32x4){0.f, 0.f, 0.f, 0.f};

    for (int k0 = 0; k0 < K; k0 += 32) {
        gload16(aptr + k0, lA);
        gload16(aptr + (size_t)16 * lda + k0, lA + 16 * 32);
        gload16(bptr + k0, lB);
        gload16(bptr + (size_t)16 * ldb + k0, lB + 16 * 32);
        __syncthreads();
        bf16x8 af[4], bfr[4];
#pragma unroll
        for (int i = 0; i < 4; ++i)
            af[i] = *(const bf16x8*)&sA[(wm + i * 16 + r16) * 32 + q4 * 8];
#pragma unroll
        for (int j = 0; j < 4; ++j)
            bfr[j] = *(const bf16x8*)&sB[(wn + j * 16 + r16) * 32 + q4 * 8];
#pragma unroll
        for (int i = 0; i < 4; ++i)
#pragma unroll
            for (int j = 0; j < 4; ++j) acc[i][j] = mfma16(af[i], bfr[j], acc[i][j]);
        __syncthreads();
    }

#pragma unroll
    for (int j = 0; j < 4; ++j) {
        int col = blockIdx.y * 128 + wn + j * 16 + r16;
        float bv = bias ? bias[col] : 0.f;
#pragma unroll
        for (int i = 0; i < 4; ++i) {
#pragma unroll
            for (int rr = 0; rr < 4; ++rr) {
                int row = blockIdx.x * 128 + wm + i * 16 + q4 * 4 + rr;
                float v = acc[i][j][rr] * alpha + bv;
                if (resid) v += resid[(size_t)row * ldc + col];
                stf(&C[(size_t)row * ldc + col], v);
            }
        }
    }
}

// ---------------------------------------------------------------------------
// Weight-fold GEMMs, 64x64 tiles, both folds in one launch (z: 0=q, 1=k).
// ---------------------------------------------------------------------------
__global__ __launch_bounds__(256) void gemm_fold(
    const US* __restrict__ rt, const US* __restrict__ wqT,
    const US* __restrict__ et, const US* __restrict__ wkT,
    US* __restrict__ comb)
{
    __shared__ __align__(16) US sA[64 * 32];
    __shared__ __align__(16) US sB[64 * 32];
    const US* A; const US* Bm; US* C; float alpha;
    if (blockIdx.z == 0) { A = rt; Bm = wqT; C = comb; alpha = ALPHA_Q; }
    else { A = et; Bm = wkT; C = comb + (size_t)1024 * 1024; alpha = 1.0f; }

    const int tid = threadIdx.x;
    const int wave = tid >> 6, lane = tid & 63;
    const int r16 = lane & 15, q4 = lane >> 4;
    const int wm = (wave >> 1) * 32, wn = (wave & 1) * 32;

    const int srow = wave * 16 + (lane >> 2);
    const int sg = lane & 3;
    const US* aptr = A + (size_t)(blockIdx.x * 64 + srow) * 1024 + sg * 8;
    const US* bptr = Bm + (size_t)(blockIdx.y * 64 + srow) * 1024 + sg * 8;
    US* lA = sA + (wave * 16) * 32;
    US* lB = sB + (wave * 16) * 32;

    f32x4 acc[2][2];
#pragma unroll
    for (int i = 0; i < 2; ++i)
#pragma unroll
        for (int j = 0; j < 2; ++j) acc[i][j] = (f32x4){0.f, 0.f, 0.f, 0.f};

    for (int k0 = 0; k0 < 1024; k0 += 32) {
        gload16(aptr + k0, lA);
        gload16(bptr + k0, lB);
        __syncthreads();
        bf16x8 af[2], bfr[2];
#pragma unroll
        for (int i = 0; i < 2; ++i)
            af[i] = *(const bf16x8*)&sA[(wm + i * 16 + r16) * 32 + q4 * 8];
#pragma unroll
        for (int j = 0; j < 2; ++j)
            bfr[j] = *(const bf16x8*)&sB[(wn + j * 16 + r16) * 32 + q4 * 8];
#pragma unroll
        for (int i = 0; i < 2; ++i)
#pragma unroll
            for (int j = 0; j < 2; ++j) acc[i][j] = mfma16(af[i], bfr[j], acc[i][j]);
        __syncthreads();
    }

#pragma unroll
    for (int j = 0; j < 2; ++j) {
        int col = blockIdx.y * 64 + wn + j * 16 + r16;
#pragma unroll
        for (int i = 0; i < 2; ++i)
#pragma unroll
            for (int rr = 0; rr < 4; ++rr) {
                int row = blockIdx.x * 64 + wm + i * 16 + q4 * 4 + rr;
                C[(size_t)row * 1024 + col] = f2bf(acc[i][j][rr] * alpha);
            }
    }
}

// ---------------------------------------------------------------------------
// Flash attention. B=2 H=16 S=2048 D=64; scores pre-scaled (log2 domain).
// Block = 4 waves x 64 q = 256 q-rows of one (b,h). Shared 64-key K/V tiles,
// double-buffered, staged by all 4 waves via global_load_lds. Sync = raw
// s_barrier + per-wave s_waitcnt vmcnt(4) (no vmcnt(0) drain). All LDS tiles
// use 128B rows with the XOR granule swizzle (R4-proven conflict-free).
// Transposed algebra: S^T = K.Q^T, O^T = V^T.P^T; P stride 64, half-granule
// XOR on writes / granule XOR on reads. Per-qt l accumulators (R5 bug fix).
// Grid 256 (8 q-chunks x 32 pairs), XCD-swizzled.
// ---------------------------------------------------------------------------
__global__ __launch_bounds__(256) void attn_kernel(
    const US* __restrict__ qkvq, const US* __restrict__ vt, US* __restrict__ out)
{
    __shared__ __align__(16) US sK[2 * 64 * 64];   // [buf][key][d]
    __shared__ __align__(16) US sV[2 * 64 * 64];   // [buf][d][key]
    __shared__ __align__(16) US sP[4 * 64 * 64];   // per-wave [q][key]
    const int tid = threadIdx.x;
    const int wave = tid >> 6, lane = tid & 63;
    const int r16 = lane & 15, q4 = lane >> 4;
    const int bid = blockIdx.x;                    // 256 blocks
    const int pair = (bid & 7) * 4 + ((bid >> 3) & 3);
    const int qc = bid >> 5;                       // 0..7
    const int h = pair & 15, b = pair >> 4;
    const int qrow0 = qc * 256 + wave * 64;
    const int c7 = r16 & 7;

    // Q B-frags [n=q][k=d], in regs for the whole key sweep
    const US* qbase = qkvq + ((size_t)(b * 2048 + qrow0)) * 3072 + h * 64;
    bf16x8 qa[4][2];
#pragma unroll
    for (int qt = 0; qt < 4; ++qt)
#pragma unroll
        for (int kh = 0; kh < 2; ++kh)
            qa[qt][kh] = *(const bf16x8*)(qbase + (size_t)(qt * 16 + r16) * 3072 + kh * 32 + q4 * 8);

    f32x4 o[4][4];
    float lacc[4];
#pragma unroll
    for (int dt = 0; dt < 4; ++dt)
#pragma unroll
        for (int qt = 0; qt < 4; ++qt) o[dt][qt] = (f32x4){0.f, 0.f, 0.f, 0.f};
#pragma unroll
    for (int qt = 0; qt < 4; ++qt) lacc[qt] = 0.f;

    // staging: wave w covers tile rows [w*16, w*16+16), 2 calls of 8 rows each
    const int l8 = lane >> 3;
    const int lg = (lane & 7) ^ l8;                // source granule (XOR swizzle)
    const US* kg = qkvq + ((size_t)(b * 2048 + wave * 16 + l8)) * 3072 + 1024 + h * 64 + lg * 8;
    const US* vg = vt + ((size_t)(b * 16 + h)) * 131072 + (size_t)(wave * 16 + l8) * 2048 + lg * 8;
    US* pl = sP + wave * 4096;

#define STAGE(kc, buf) do {                                                   \
        US* dK = sK + (buf) * 4096 + (wave * 16) * 64;                        \
        US* dV = sV + (buf) * 4096 + (wave * 16) * 64;                        \
        gload16(kg + (size_t)(kc) * 3072, dK);                                \
        gload16(kg + (size_t)((kc) + 8) * 3072, dK + 8 * 64);                 \
        gload16(vg + (kc), dV);                                               \
        gload16(vg + (size_t)8 * 2048 + (kc), dV + 8 * 64);                   \
    } while (0)

    STAGE(0, 0);
    STAGE(64, 1);
    for (int it = 0; it < 32; ++it) {
        if (it < 31) asm volatile("s_waitcnt vmcnt(4)" ::: "memory");
        else         asm volatile("s_waitcnt vmcnt(0)" ::: "memory");
        asm volatile("s_barrier" ::: "memory");    // tile `it` visible to all
        const US* K0 = sK + (it & 1) * 4096;
        const US* V0 = sV + (it & 1) * 4096;

        // S^T = K.Q^T per 16-key group; exp2 -> packed b64 P-writes
#pragma unroll
        for (int kt = 0; kt < 4; ++kt) {
            bf16x8 kf0 = *(const bf16x8*)&K0[(kt * 16 + r16) * 64 + ((0 + q4) ^ c7) * 8];
            bf16x8 kf1 = *(const bf16x8*)&K0[(kt * 16 + r16) * 64 + ((4 + q4) ^ c7) * 8];
#pragma unroll
            for (int qt = 0; qt < 4; ++qt) {
                f32x4 st = mfma16(kf0, qa[qt][0], (f32x4){0.f, 0.f, 0.f, 0.f});
                st = mfma16(kf1, qa[qt][1], st);
                float p0 = EXP2F(st[0]), p1 = EXP2F(st[1]);
                float p2 = EXP2F(st[2]), p3 = EXP2F(st[3]);
                lacc[qt] += (p0 + p1) + (p2 + p3);
                uint2v w;
                w.x = bftr(p0) | (bftr(p1) << 16);
                w.y = bftr(p2) | (bftr(p3) << 16);
                // half-granule (8B) XOR swizzle: hg' = (kt*4+q4) ^ (2*c7)
                *(uint2v*)&pl[(qt * 16 + r16) * 64 + (((kt * 4 + q4) ^ (c7 << 1)) << 2)] = w;
            }
        }
        asm volatile("s_waitcnt lgkmcnt(0)" ::: "memory");  // wave-local P vis

        // O^T += V^T.P^T
        bf16x8 pa[4][2];
#pragma unroll
        for (int qt = 0; qt < 4; ++qt)
#pragma unroll
            for (int ks = 0; ks < 2; ++ks)
                pa[qt][ks] = *(const bf16x8*)&pl[(qt * 16 + r16) * 64 + ((ks * 4 + q4) ^ c7) * 8];
#pragma unroll
        for (int dt = 0; dt < 4; ++dt)
#pragma unroll
            for (int ks = 0; ks < 2; ++ks) {
                bf16x8 vf = *(const bf16x8*)&V0[(dt * 16 + r16) * 64 + ((ks * 4 + q4) ^ c7) * 8];
#pragma unroll
                for (int qt = 0; qt < 4; ++qt)
                    o[dt][qt] = mfma16(vf, pa[qt][ks], o[dt][qt]);
            }

        asm volatile("s_barrier" ::: "memory");    // all waves done reading buf
        if (it < 30) STAGE((it + 2) * 64, it & 1);
    }
#undef STAGE

    // epilogue: per-qt l reduce over the 4 quad groups, normalize, store
#pragma unroll
    for (int qt = 0; qt < 4; ++qt) {
        float l = lacc[qt];
        l += __shfl_xor(l, 16);
        l += __shfl_xor(l, 32);
        const float inv = 1.0f / l;
        const size_t row = (size_t)(b * 2048 + qrow0 + qt * 16 + r16);
#pragma unroll
        for (int dt = 0; dt < 4; ++dt) {
            uint2v w;
            w.x = (unsigned)f2bf(o[dt][qt][0] * inv) | ((unsigned)f2bf(o[dt][qt][1] * inv) << 16);
            w.y = (unsigned)f2bf(o[dt][qt][2] * inv) | ((unsigned)f2bf(o[dt][qt][3] * inv) << 16);
            *(uint2v*)&out[row * 1024 + h * 64 + dt * 16 + q4 * 4] = w;
        }
    }
}

// ---------------------------------------------------------------------------
// B=2, S=2048, E=1024, H=16, D=64. Inputs fp32, output fp32.
// ---------------------------------------------------------------------------
extern "C" void kernel_launch(void* const* d_in, const int* in_sizes, int n_in,
                              void* d_out, int out_size, void* d_ws, size_t ws_size,
                              hipStream_t stream)
{
    const float* x    = (const float*)d_in[0];
    const float* Rm   = (const float*)d_in[1];
    const float* Em   = (const float*)d_in[2];
    const float* qkvw = (const float*)d_in[3];
    const float* qkvb = (const float*)d_in[4];
    const float* outw = (const float*)d_in[5];
    const float* outb = (const float*)d_in[6];
    float* outp = (float*)d_out;

    US* ws    = (US*)d_ws;
    US* xb    = ws;
    US* rt    = xb   + (size_t)4096 * 1024;
    US* et    = rt   + (size_t)1024 * 1024;
    US* wqT   = et   + (size_t)1024 * 1024;
    US* wkT   = wqT  + (size_t)1024 * 1024;
    US* wo    = wkT  + (size_t)1024 * 1024;
    US* comb  = wo   + (size_t)1024 * 1024;   // 3072 x 1024 fused weight
    US* qkvq  = comb + (size_t)3072 * 1024;   // 4096 x 3072: q' | k' | v
    US* vt    = qkvq + (size_t)4096 * 3072;
    US* ao    = vt   + (size_t)4096 * 1024;
    float* b3 = (float*)(ao + (size_t)4096 * 1024);

    // zero the accumulated bias region (atomicAdd targets)
    hipMemsetAsync(b3, 0, 2048 * sizeof(float), stream);
    // casts + 4 transposes + bias-GEMV partials + v-bias in one launch
    prep<<<dim3(7300), dim3(256), 0, stream>>>(
        x, xb, qkvw, comb + (size_t)2048 * 1024, outw, wo,
        Rm, rt, Em, et, wqT, wkT, qkvb, b3);
    // comb_q = ALPHA_Q * R^T Wq ; comb_k = E^T Wk
    gemm_fold<<<dim3(16, 16, 2), dim3(256), 0, stream>>>(rt, wqT, et, wkT, comb);
    // qkvq = x @ comb^T + b3  -> q' | k' | v
    gemm_nt<US><<<dim3(32, 24), dim3(256), 0, stream>>>(xb, comb, qkvq, b3, nullptr, 1.0f,
                                                        4096, 3072, 1024, 1024, 1024, 3072);
    // vt[b, d_feat, s] = v[b, s, d_feat]
    transpose_bf<<<dim3(16, 32, 2), dim3(256), 0, stream>>>(qkvq + 2048, vt, 3072, 2048,
                                                            (long)2048 * 3072, (long)1024 * 2048);
    // attention
    attn_kernel<<<dim3(256), dim3(256), 0, stream>>>(qkvq, vt, ao);
    // out = ao @ out_w^T + out_b + x
    gemm_nt<float><<<dim3(32, 8), dim3(256), 0, stream>>>(ao, wo, outp, outb, x, 1.0f,
                                                          4096, 1024, 1024, 1024, 1024, 1024);
}

// Round 7
// 253.498 us; speedup vs baseline: 1.2028x; 1.0692x over previous
//
#include <hip/hip_runtime.h>

#define US unsigned short
#define UC unsigned char

typedef __bf16 bf16x8 __attribute__((ext_vector_type(8)));
typedef float f32x4 __attribute__((ext_vector_type(4)));
typedef unsigned int u32x4 __attribute__((ext_vector_type(4)));
typedef unsigned short u16x4 __attribute__((ext_vector_type(4)));
typedef unsigned int uint2v __attribute__((ext_vector_type(2)));

// 0.125 (softmax 1/sqrt(D)) * log2(e): folded into W'q and b'q -> P = exp2(s).
#define ALPHA_Q 0.180336880111f

#if __has_builtin(__builtin_amdgcn_exp2f)
#define EXP2F(x) __builtin_amdgcn_exp2f(x)
#else
#define EXP2F(x) __expf(0.69314718f * (x))
#endif

static __device__ __forceinline__ US f2bf(float f) {  // RTNE
    union { float f; unsigned u; } v; v.f = f;
    unsigned r = v.u + 0x7fffu + ((v.u >> 16) & 1u);
    return (US)(r >> 16);
}
static __device__ __forceinline__ float bf2f(US h) {
    union { unsigned u; float f; } v; v.u = ((unsigned)h) << 16;
    return v.f;
}
static __device__ __forceinline__ f32x4 mfma16(bf16x8 a, bf16x8 b, f32x4 c) {
    return __builtin_amdgcn_mfma_f32_16x16x32_bf16(a, b, c, 0, 0, 0);
}
static __device__ __forceinline__ f32x4 mfma_fp8(long long a, long long b, f32x4 c) {
    return __builtin_amdgcn_mfma_f32_16x16x32_fp8_fp8(a, b, c, 0, 0, 0);
}
// async global->LDS, 16B/lane; LDS dest = base + lane*16 (wave-uniform base)
static __device__ __forceinline__ void gload16(const US* g, US* l) {
    __builtin_amdgcn_global_load_lds(
        (const __attribute__((address_space(1))) void*)g,
        (__attribute__((address_space(3))) void*)l, 16, 0, 0);
}
static __device__ __forceinline__ void gload16b(const UC* g, UC* l) {
    __builtin_amdgcn_global_load_lds(
        (const __attribute__((address_space(1))) void*)g,
        (__attribute__((address_space(3))) void*)l, 16, 0, 0);
}
static __device__ __forceinline__ void stf(float* p, float v) { *p = v; }
static __device__ __forceinline__ void stf(US* p, float v) { *p = f2bf(v); }

// ---------------------------------------------------------------------------
// Fused prep: [0,6144) f32->bf16 casts; [6144,7168) 4 transposes;
// [7168,7296) bias-GEMV partials (atomicAdd into pre-zeroed b3);
// [7296,7300) v-bias copy.
// ---------------------------------------------------------------------------
__global__ __launch_bounds__(256) void prep(
    const float* __restrict__ x, US* __restrict__ xb,
    const float* __restrict__ qkvw, US* __restrict__ wv,
    const float* __restrict__ outw, US* __restrict__ wo,
    const float* __restrict__ Rm, US* __restrict__ rt,
    const float* __restrict__ Em, US* __restrict__ et,
    US* __restrict__ wqT, US* __restrict__ wkT,
    const float* __restrict__ qkvb, float* __restrict__ b3)
{
    __shared__ float t[64][65];
    const int bx = blockIdx.x;
    if (bx < 6144) {            // bulk casts: x (4096 blks), Wv (1024), Wo (1024)
        int i = bx * 256 + threadIdx.x;
        const float* s; US* d; int j;
        if (i < 1048576) { s = x; d = xb; j = i; }
        else if (i < 1310720) { s = qkvw + (size_t)2048 * 1024; d = wv; j = i - 1048576; }
        else { s = outw; d = wo; j = i - 1310720; }
        f32x4 v = ((const f32x4*)s)[j];
        u16x4 o;
        o.x = f2bf(v.x); o.y = f2bf(v.y); o.z = f2bf(v.z); o.w = f2bf(v.w);
        ((u16x4*)d)[j] = o;
    } else if (bx < 7168) {     // 4 x 1024x1024 fp32->bf16 transposes
        int r = bx - 6144;
        int z = r >> 8, xy = r & 255, tbx = xy & 15, tby = xy >> 4;
        const float* ip; US* op;
        switch (z) {
            case 0: ip = Rm; op = rt; break;
            case 1: ip = Em; op = et; break;
            case 2: ip = qkvw; op = wqT; break;
            default: ip = qkvw + (size_t)1024 * 1024; op = wkT; break;
        }
        int bc = tbx * 64, br = tby * 64;
        int lx = threadIdx.x & 63, y4 = threadIdx.x >> 6;
#pragma unroll
        for (int i = 0; i < 16; ++i) {
            int rr = i * 4 + y4;
            t[rr][lx] = ip[(size_t)(br + rr) * 1024 + bc + lx];
        }
        __syncthreads();
#pragma unroll
        for (int i = 0; i < 16; ++i) {
            int c = i * 4 + y4;
            op[(size_t)(bc + c) * 1024 + br + lx] = f2bf(t[lx][c]);
        }
    } else if (bx < 7296) {     // bias GEMV partials: 32 n-chunks x 4 j-chunks
        float (*red)[64] = (float(*)[64])t;
        const int bb = bx - 7168;
        const int tid = threadIdx.x, wave = tid >> 6, lane = tid & 63;
        const int nc = bb & 31, jc = bb >> 5;
        const int n0 = nc * 64, n = n0 + lane;
        const float* M = (n0 < 1024) ? Rm : Em;
        const float* bv = qkvb + ((n0 < 1024) ? 0 : 1024);
        const int nn = (n0 < 1024) ? n : n - 1024;
        float s = 0.f;
        const int j0 = jc * 256 + wave * 64;
#pragma unroll 8
        for (int j = 0; j < 64; ++j)
            s += bv[j0 + j] * M[(size_t)(j0 + j) * 1024 + nn];
        red[wave][lane] = s;
        __syncthreads();
        if (wave == 0) {
            float tt = red[0][lane] + red[1][lane] + red[2][lane] + red[3][lane];
            atomicAdd(&b3[n], (n0 < 1024) ? tt * ALPHA_Q : tt);
        }
    } else {                    // v-bias copy
        int i = (bx - 7296) * 256 + threadIdx.x;
        b3[2048 + i] = qkvb[2048 + i];
    }
}

// ---------------------------------------------------------------------------
// NT GEMM 128x128 tile (m97-style): C = alpha*A.B^T (+bias) (+resid).
// ---------------------------------------------------------------------------
template <typename TO>
__global__ __launch_bounds__(256) void gemm_nt(
    const US* __restrict__ A, const US* __restrict__ Bm,
    TO* __restrict__ C, const float* __restrict__ bias,
    const float* __restrict__ resid, float alpha,
    int M, int N, int K, int lda, int ldb, int ldc)
{
    __shared__ __align__(16) US sA[128 * 32];
    __shared__ __align__(16) US sB[128 * 32];
    const int tid = threadIdx.x;
    const int wave = tid >> 6, lane = tid & 63;
    const int r16 = lane & 15, q4 = lane >> 4;
    const int wm = (wave >> 1) * 64, wn = (wave & 1) * 64;

    const int srow = wave * 32 + (lane >> 2);
    const int sg = lane & 3;
    const US* aptr = A + (size_t)(blockIdx.x * 128 + srow) * lda + sg * 8;
    const US* bptr = Bm + (size_t)(blockIdx.y * 128 + srow) * ldb + sg * 8;
    US* lA = sA + (wave * 32) * 32;
    US* lB = sB + (wave * 32) * 32;

    f32x4 acc[4][4];
#pragma unroll
    for (int i = 0; i < 4; ++i)
#pragma unroll
        for (int j = 0; j < 4; ++j) acc[i][j] = (f32x4){0.f, 0.f, 0.f, 0.f};

    for (int k0 = 0; k0 < K; k0 += 32) {
        gload16(aptr + k0, lA);
        gload16(aptr + (size_t)16 * lda + k0, lA + 16 * 32);
        gload16(bptr + k0, lB);
        gload16(bptr + (size_t)16 * ldb + k0, lB + 16 * 32);
        __syncthreads();
        bf16x8 af[4], bfr[4];
#pragma unroll
        for (int i = 0; i < 4; ++i)
            af[i] = *(const bf16x8*)&sA[(wm + i * 16 + r16) * 32 + q4 * 8];
#pragma unroll
        for (int j = 0; j < 4; ++j)
            bfr[j] = *(const bf16x8*)&sB[(wn + j * 16 + r16) * 32 + q4 * 8];
#pragma unroll
        for (int i = 0; i < 4; ++i)
#pragma unroll
            for (int j = 0; j < 4; ++j) acc[i][j] = mfma16(af[i], bfr[j], acc[i][j]);
        __syncthreads();
    }

#pragma unroll
    for (int j = 0; j < 4; ++j) {
        int col = blockIdx.y * 128 + wn + j * 16 + r16;
        float bv = bias ? bias[col] : 0.f;
#pragma unroll
        for (int i = 0; i < 4; ++i) {
#pragma unroll
            for (int rr = 0; rr < 4; ++rr) {
                int row = blockIdx.x * 128 + wm + i * 16 + q4 * 4 + rr;
                float v = acc[i][j][rr] * alpha + bv;
                if (resid) v += resid[(size_t)row * ldc + col];
                stf(&C[(size_t)row * ldc + col], v);
            }
        }
    }
}

// ---------------------------------------------------------------------------
// qkv GEMM with split epilogue: cols [0,2048) -> bf16 qk buffer [4096][2048];
// cols [2048,3072) -> V written TRANSPOSED as fp8 into vt[b][feat][s]
// (4 consecutive s per lane -> packed b32). Grid (32,24).
// ---------------------------------------------------------------------------
__global__ __launch_bounds__(256) void gemm_qkv(
    const US* __restrict__ A, const US* __restrict__ Bm,
    const float* __restrict__ bias,
    US* __restrict__ qk, UC* __restrict__ vt)
{
    __shared__ __align__(16) US sA[128 * 32];
    __shared__ __align__(16) US sB[128 * 32];
    const int tid = threadIdx.x;
    const int wave = tid >> 6, lane = tid & 63;
    const int r16 = lane & 15, q4 = lane >> 4;
    const int wm = (wave >> 1) * 64, wn = (wave & 1) * 64;

    const int srow = wave * 32 + (lane >> 2);
    const int sg = lane & 3;
    const US* aptr = A + (size_t)(blockIdx.x * 128 + srow) * 1024 + sg * 8;
    const US* bptr = Bm + (size_t)(blockIdx.y * 128 + srow) * 1024 + sg * 8;
    US* lA = sA + (wave * 32) * 32;
    US* lB = sB + (wave * 32) * 32;

    f32x4 acc[4][4];
#pragma unroll
    for (int i = 0; i < 4; ++i)
#pragma unroll
        for (int j = 0; j < 4; ++j) acc[i][j] = (f32x4){0.f, 0.f, 0.f, 0.f};

    for (int k0 = 0; k0 < 1024; k0 += 32) {
        gload16(aptr + k0, lA);
        gload16(aptr + (size_t)16 * 1024 + k0, lA + 16 * 32);
        gload16(bptr + k0, lB);
        gload16(bptr + (size_t)16 * 1024 + k0, lB + 16 * 32);
        __syncthreads();
        bf16x8 af[4], bfr[4];
#pragma unroll
        for (int i = 0; i < 4; ++i)
            af[i] = *(const bf16x8*)&sA[(wm + i * 16 + r16) * 32 + q4 * 8];
#pragma unroll
        for (int j = 0; j < 4; ++j)
            bfr[j] = *(const bf16x8*)&sB[(wn + j * 16 + r16) * 32 + q4 * 8];
#pragma unroll
        for (int i = 0; i < 4; ++i)
#pragma unroll
            for (int j = 0; j < 4; ++j) acc[i][j] = mfma16(af[i], bfr[j], acc[i][j]);
        __syncthreads();
    }

    if (blockIdx.y < 16) {          // q' | k' -> bf16 row-major
#pragma unroll
        for (int j = 0; j < 4; ++j) {
            int col = blockIdx.y * 128 + wn + j * 16 + r16;
            float bv = bias[col];
#pragma unroll
            for (int i = 0; i < 4; ++i)
#pragma unroll
                for (int rr = 0; rr < 4; ++rr) {
                    int row = blockIdx.x * 128 + wm + i * 16 + q4 * 4 + rr;
                    qk[(size_t)row * 2048 + col] = f2bf(acc[i][j][rr] + bv);
                }
        }
    } else {                        // v -> fp8, transposed into vt[b][f][s]
#pragma unroll
        for (int j = 0; j < 4; ++j) {
            int col = blockIdx.y * 128 + wn + j * 16 + r16;
            float bv = bias[col];
            int f = col - 2048;
#pragma unroll
            for (int i = 0; i < 4; ++i) {
                int row0 = blockIdx.x * 128 + wm + i * 16 + q4 * 4;
                int b = row0 >> 11, s0 = row0 & 2047;
                int dw = __builtin_amdgcn_cvt_pk_fp8_f32(
                    acc[i][j][0] + bv, acc[i][j][1] + bv, 0, false);
                dw = __builtin_amdgcn_cvt_pk_fp8_f32(
                    acc[i][j][2] + bv, acc[i][j][3] + bv, dw, true);
                *(unsigned int*)&vt[((size_t)(b * 1024 + f)) * 2048 + s0] = (unsigned)dw;
            }
        }
    }
}

// ---------------------------------------------------------------------------
// Weight-fold GEMMs, 64x64 tiles, both folds in one launch (z: 0=q, 1=k).
// ---------------------------------------------------------------------------
__global__ __launch_bounds__(256) void gemm_fold(
    const US* __restrict__ rt, const US* __restrict__ wqT,
    const US* __restrict__ et, const US* __restrict__ wkT,
    US* __restrict__ comb)
{
    __shared__ __align__(16) US sA[64 * 32];
    __shared__ __align__(16) US sB[64 * 32];
    const US* A; const US* Bm; US* C; float alpha;
    if (blockIdx.z == 0) { A = rt; Bm = wqT; C = comb; alpha = ALPHA_Q; }
    else { A = et; Bm = wkT; C = comb + (size_t)1024 * 1024; alpha = 1.0f; }

    const int tid = threadIdx.x;
    const int wave = tid >> 6, lane = tid & 63;
    const int r16 = lane & 15, q4 = lane >> 4;
    const int wm = (wave >> 1) * 32, wn = (wave & 1) * 32;

    const int srow = wave * 16 + (lane >> 2);
    const int sg = lane & 3;
    const US* aptr = A + (size_t)(blockIdx.x * 64 + srow) * 1024 + sg * 8;
    const US* bptr = Bm + (size_t)(blockIdx.y * 64 + srow) * 1024 + sg * 8;
    US* lA = sA + (wave * 16) * 32;
    US* lB = sB + (wave * 16) * 32;

    f32x4 acc[2][2];
#pragma unroll
    for (int i = 0; i < 2; ++i)
#pragma unroll
        for (int j = 0; j < 2; ++j) acc[i][j] = (f32x4){0.f, 0.f, 0.f, 0.f};

    for (int k0 = 0; k0 < 1024; k0 += 32) {
        gload16(aptr + k0, lA);
        gload16(bptr + k0, lB);
        __syncthreads();
        bf16x8 af[2], bfr[2];
#pragma unroll
        for (int i = 0; i < 2; ++i)
            af[i] = *(const bf16x8*)&sA[(wm + i * 16 + r16) * 32 + q4 * 8];
#pragma unroll
        for (int j = 0; j < 2; ++j)
            bfr[j] = *(const bf16x8*)&sB[(wn + j * 16 + r16) * 32 + q4 * 8];
#pragma unroll
        for (int i = 0; i < 2; ++i)
#pragma unroll
            for (int j = 0; j < 2; ++j) acc[i][j] = mfma16(af[i], bfr[j], acc[i][j]);
        __syncthreads();
    }

#pragma unroll
    for (int j = 0; j < 2; ++j) {
        int col = blockIdx.y * 64 + wn + j * 16 + r16;
#pragma unroll
        for (int i = 0; i < 2; ++i)
#pragma unroll
            for (int rr = 0; rr < 4; ++rr) {
                int row = blockIdx.x * 64 + wm + i * 16 + q4 * 4 + rr;
                C[(size_t)row * 1024 + col] = f2bf(acc[i][j][rr] * alpha);
            }
    }
}

// ---------------------------------------------------------------------------
// Flash attention. B=2 H=16 S=2048 D=64; scores pre-scaled (log2 domain).
// Block = 2 waves x 64 q = 128 q-rows; grid 512 = 2 blocks/CU; XCD swizzle.
// QK^T bf16 (K: 128B rows, 16B-granule XOR swizzle); PV in fp8 e4m3:
// V fp8 staged via global_load_lds (64B rows, 16B-chunk XOR), P fp8 LDS
// round-trip in 72B-padded rows (uniform bank mapping, writes b32/reads b64).
// Raw s_barrier + s_waitcnt vmcnt(6) double-buffer (no vmcnt(0) drain).
// Per-qt l accumulators; deferred softmax denominator (no online max).
// ---------------------------------------------------------------------------
__global__ __launch_bounds__(128) void attn_kernel(
    const US* __restrict__ qk, const UC* __restrict__ vt, US* __restrict__ out)
{
    __shared__ __align__(16) US sK[2 * 64 * 64];   // bf16 [buf][key][d]  16 KB
    __shared__ __align__(16) UC sV[2 * 64 * 64];   // fp8  [buf][d][key]   8 KB
    __shared__ __align__(16) UC sP[2 * 64 * 72];   // fp8 per-wave [q][72] 9 KB
    const int tid = threadIdx.x;
    const int wave = tid >> 6, lane = tid & 63;
    const int r16 = lane & 15, q4 = lane >> 4;
    const int bid = blockIdx.x;                    // 512 blocks
    const int pair = (bid & 7) * 4 + ((bid >> 3) & 3);
    const int qc = bid >> 5;                       // 0..15
    const int h = pair & 15, b = pair >> 4;
    const int qrow0 = qc * 128 + wave * 64;
    const int c7 = r16 & 7, c3 = r16 & 3;

    // Q B-frags [n=q][k=d] (bf16), resident all sweep
    const US* qbase = qk + ((size_t)(b * 2048 + qrow0)) * 2048 + h * 64;
    bf16x8 qa[4][2];
#pragma unroll
    for (int qt = 0; qt < 4; ++qt)
#pragma unroll
        for (int kh = 0; kh < 2; ++kh)
            qa[qt][kh] = *(const bf16x8*)(qbase + (size_t)(qt * 16 + r16) * 2048 + kh * 32 + q4 * 8);

    f32x4 o[4][4];
    float lacc[4];
#pragma unroll
    for (int dt = 0; dt < 4; ++dt)
#pragma unroll
        for (int qt = 0; qt < 4; ++qt) o[dt][qt] = (f32x4){0.f, 0.f, 0.f, 0.f};
#pragma unroll
    for (int qt = 0; qt < 4; ++qt) lacc[qt] = 0.f;

    // staging lane constants
    const int l8 = lane >> 3;                       // K: 8 rows / call (128B rows)
    const US* kg = qk + ((size_t)(b * 2048 + wave * 32 + l8)) * 2048 + 1024 + h * 64
                 + (((lane & 7) ^ l8)) * 8;
    const int r4 = lane >> 2;                       // V: 16 rows / call (64B rows)
    const UC* vg = vt + ((size_t)((b * 16 + h) * 64 + wave * 32 + r4)) * 2048
                 + (((lane & 3) ^ (r4 & 3))) * 16;
    UC* pl = sP + wave * 4608;

#define STAGE(kc, buf) do {                                                    \
        US* dK = sK + (buf) * 4096 + (wave * 32) * 64;                         \
        UC* dV = sV + (buf) * 4096 + (wave * 32) * 64;                         \
        _Pragma("unroll")                                                      \
        for (int c = 0; c < 4; ++c)                                            \
            gload16(kg + (size_t)((kc) + c * 8) * 2048, dK + c * 8 * 64);      \
        _Pragma("unroll")                                                      \
        for (int c = 0; c < 2; ++c)                                            \
            gload16b(vg + (size_t)(c * 16) * 2048 + (kc), dV + c * 16 * 64);   \
    } while (0)

    STAGE(0, 0);
    STAGE(64, 1);
    for (int it = 0; it < 32; ++it) {
        const int buf = it & 1;
        if (it < 31) asm volatile("s_waitcnt vmcnt(6)" ::: "memory");
        else         asm volatile("s_waitcnt vmcnt(0)" ::: "memory");
        asm volatile("s_barrier" ::: "memory");
        const US* K0 = sK + buf * 4096;
        const UC* V0 = sV + buf * 4096;

        // S^T = K.Q^T (bf16); exp2 -> fp8 pack -> padded P rows (b32 writes)
#pragma unroll
        for (int kt = 0; kt < 4; ++kt) {
            bf16x8 kf0 = *(const bf16x8*)&K0[(kt * 16 + r16) * 64 + ((0 + q4) ^ c7) * 8];
            bf16x8 kf1 = *(const bf16x8*)&K0[(kt * 16 + r16) * 64 + ((4 + q4) ^ c7) * 8];
#pragma unroll
            for (int qt = 0; qt < 4; ++qt) {
                f32x4 st = mfma16(kf0, qa[qt][0], (f32x4){0.f, 0.f, 0.f, 0.f});
                st = mfma16(kf1, qa[qt][1], st);
                float p0 = EXP2F(st[0]), p1 = EXP2F(st[1]);
                float p2 = EXP2F(st[2]), p3 = EXP2F(st[3]);
                lacc[qt] += (p0 + p1) + (p2 + p3);
                int dw = __builtin_amdgcn_cvt_pk_fp8_f32(p0, p1, 0, false);
                dw = __builtin_amdgcn_cvt_pk_fp8_f32(p2, p3, dw, true);
                *(unsigned int*)&pl[(qt * 16 + r16) * 72 + kt * 16 + q4 * 4] = (unsigned)dw;
            }
        }
        asm volatile("s_waitcnt lgkmcnt(0)" ::: "memory");  // wave-local P vis

        // O^T += V^T.P^T (fp8 MFMA)
        long long pa[4][2];
#pragma unroll
        for (int qt = 0; qt < 4; ++qt)
#pragma unroll
            for (int ks = 0; ks < 2; ++ks)
                pa[qt][ks] = *(const long long*)&pl[(qt * 16 + r16) * 72 + ks * 32 + q4 * 8];
#pragma unroll
        for (int dt = 0; dt < 4; ++dt)
#pragma unroll
            for (int ks = 0; ks < 2; ++ks) {
                int g8 = ks * 4 + q4;
                long long vf = *(const long long*)&V0[(dt * 16 + r16) * 64
                              + (((g8 >> 1) ^ c3) << 4) + ((g8 & 1) << 3)];
#pragma unroll
                for (int qt = 0; qt < 4; ++qt)
                    o[dt][qt] = mfma_fp8(vf, pa[qt][ks], o[dt][qt]);
            }

        asm volatile("s_barrier" ::: "memory");
        if (it < 30) STAGE((it + 2) * 64, buf);
    }
#undef STAGE

    // epilogue: per-qt l reduce across the 4 quad groups, normalize, store
#pragma unroll
    for (int qt = 0; qt < 4; ++qt) {
        float l = lacc[qt];
        l += __shfl_xor(l, 16);
        l += __shfl_xor(l, 32);
        const float inv = 1.0f / l;
        const size_t row = (size_t)(b * 2048 + qrow0 + qt * 16 + r16);
#pragma unroll
        for (int dt = 0; dt < 4; ++dt) {
            uint2v w;
            w.x = (unsigned)f2bf(o[dt][qt][0] * inv) | ((unsigned)f2bf(o[dt][qt][1] * inv) << 16);
            w.y = (unsigned)f2bf(o[dt][qt][2] * inv) | ((unsigned)f2bf(o[dt][qt][3] * inv) << 16);
            *(uint2v*)&out[row * 1024 + h * 64 + dt * 16 + q4 * 4] = w;
        }
    }
}

// ---------------------------------------------------------------------------
// B=2, S=2048, E=1024, H=16, D=64. Inputs fp32, output fp32. 5 kernels.
// ws (US units): xb 4M | rt 1M | et 1M | wqT 1M | wkT 1M | wo 1M | comb 3M
//   | qkvq(q|k bf16) 8M | ao 4M | vt(fp8) 2M | b3 (fp32 3072)
// ---------------------------------------------------------------------------
extern "C" void kernel_launch(void* const* d_in, const int* in_sizes, int n_in,
                              void* d_out, int out_size, void* d_ws, size_t ws_size,
                              hipStream_t stream)
{
    const float* x    = (const float*)d_in[0];
    const float* Rm   = (const float*)d_in[1];
    const float* Em   = (const float*)d_in[2];
    const float* qkvw = (const float*)d_in[3];
    const float* qkvb = (const float*)d_in[4];
    const float* outw = (const float*)d_in[5];
    const float* outb = (const float*)d_in[6];
    float* outp = (float*)d_out;

    US* ws    = (US*)d_ws;
    US* xb    = ws;
    US* rt    = xb   + (size_t)4096 * 1024;
    US* et    = rt   + (size_t)1024 * 1024;
    US* wqT   = et   + (size_t)1024 * 1024;
    US* wkT   = wqT  + (size_t)1024 * 1024;
    US* wo    = wkT  + (size_t)1024 * 1024;
    US* comb  = wo   + (size_t)1024 * 1024;   // 3072 x 1024 fused weight
    US* qkvq  = comb + (size_t)3072 * 1024;   // 4096 x 2048: q' | k' (bf16)
    US* ao    = qkvq + (size_t)4096 * 2048;
    UC* vt    = (UC*)(ao + (size_t)4096 * 1024);   // fp8 [b][feat][s], 4 MB
    float* b3 = (float*)(vt + (size_t)2048 * 2048);

    // zero the accumulated bias region (atomicAdd targets)
    hipMemsetAsync(b3, 0, 2048 * sizeof(float), stream);
    // casts + 4 transposes + bias-GEMV partials + v-bias in one launch
    prep<<<dim3(7300), dim3(256), 0, stream>>>(
        x, xb, qkvw, comb + (size_t)2048 * 1024, outw, wo,
        Rm, rt, Em, et, wqT, wkT, qkvb, b3);
    // comb_q = ALPHA_Q * R^T Wq ; comb_k = E^T Wk
    gemm_fold<<<dim3(16, 16, 2), dim3(256), 0, stream>>>(rt, wqT, et, wkT, comb);
    // qkv: q'|k' -> qkvq (bf16), v -> vt (fp8, transposed) in one GEMM
    gemm_qkv<<<dim3(32, 24), dim3(256), 0, stream>>>(xb, comb, b3, qkvq, vt);
    // attention
    attn_kernel<<<dim3(512), dim3(128), 0, stream>>>(qkvq, vt, ao);
    // out = ao @ out_w^T + out_b + x
    gemm_nt<float><<<dim3(32, 8), dim3(256), 0, stream>>>(ao, wo, outp, outb, x, 1.0f,
                                                          4096, 1024, 1024, 1024, 1024, 1024);
}

// Round 8
// 232.217 us; speedup vs baseline: 1.3131x; 1.0916x over previous
//
#include <hip/hip_runtime.h>

#define US unsigned short
#define UC unsigned char

typedef __bf16 bf16x8 __attribute__((ext_vector_type(8)));
typedef float f32x4 __attribute__((ext_vector_type(4)));
typedef unsigned int u32x4 __attribute__((ext_vector_type(4)));
typedef unsigned short u16x4 __attribute__((ext_vector_type(4)));
typedef unsigned int uint2v __attribute__((ext_vector_type(2)));

// 0.125 (softmax 1/sqrt(D)) * log2(e): folded into W'q and b'q -> P = exp2(s).
#define ALPHA_Q 0.180336880111f

#if __has_builtin(__builtin_amdgcn_exp2f)
#define EXP2F(x) __builtin_amdgcn_exp2f(x)
#else
#define EXP2F(x) __expf(0.69314718f * (x))
#endif

static __device__ __forceinline__ US f2bf(float f) {  // RTNE
    union { float f; unsigned u; } v; v.f = f;
    unsigned r = v.u + 0x7fffu + ((v.u >> 16) & 1u);
    return (US)(r >> 16);
}
static __device__ __forceinline__ float bf2f(US h) {
    union { unsigned u; float f; } v; v.u = ((unsigned)h) << 16;
    return v.f;
}
static __device__ __forceinline__ f32x4 mfma16(bf16x8 a, bf16x8 b, f32x4 c) {
    return __builtin_amdgcn_mfma_f32_16x16x32_bf16(a, b, c, 0, 0, 0);
}
static __device__ __forceinline__ f32x4 mfma_fp8(long long a, long long b, f32x4 c) {
    return __builtin_amdgcn_mfma_f32_16x16x32_fp8_fp8(a, b, c, 0, 0, 0);
}
// async global->LDS, 16B/lane; LDS dest = base + lane*16 (wave-uniform base)
static __device__ __forceinline__ void gload16(const US* g, US* l) {
    __builtin_amdgcn_global_load_lds(
        (const __attribute__((address_space(1))) void*)g,
        (__attribute__((address_space(3))) void*)l, 16, 0, 0);
}
static __device__ __forceinline__ void gload16b(const UC* g, UC* l) {
    __builtin_amdgcn_global_load_lds(
        (const __attribute__((address_space(1))) void*)g,
        (__attribute__((address_space(3))) void*)l, 16, 0, 0);
}
static __device__ __forceinline__ void stf(float* p, float v) { *p = v; }
static __device__ __forceinline__ void stf(US* p, float v) { *p = f2bf(v); }

// ---------------------------------------------------------------------------
// Fused prep: [0,6144) f32->bf16 casts; [6144,7168) 4 transposes;
// [7168,7296) bias-GEMV partials (atomicAdd into pre-zeroed b3);
// [7296,7300) v-bias copy.
// ---------------------------------------------------------------------------
__global__ __launch_bounds__(256) void prep(
    const float* __restrict__ x, US* __restrict__ xb,
    const float* __restrict__ qkvw, US* __restrict__ wv,
    const float* __restrict__ outw, US* __restrict__ wo,
    const float* __restrict__ Rm, US* __restrict__ rt,
    const float* __restrict__ Em, US* __restrict__ et,
    US* __restrict__ wqT, US* __restrict__ wkT,
    const float* __restrict__ qkvb, float* __restrict__ b3)
{
    __shared__ float t[64][65];
    const int bx = blockIdx.x;
    if (bx < 6144) {            // bulk casts: x (4096 blks), Wv (1024), Wo (1024)
        int i = bx * 256 + threadIdx.x;
        const float* s; US* d; int j;
        if (i < 1048576) { s = x; d = xb; j = i; }
        else if (i < 1310720) { s = qkvw + (size_t)2048 * 1024; d = wv; j = i - 1048576; }
        else { s = outw; d = wo; j = i - 1310720; }
        f32x4 v = ((const f32x4*)s)[j];
        u16x4 o;
        o.x = f2bf(v.x); o.y = f2bf(v.y); o.z = f2bf(v.z); o.w = f2bf(v.w);
        ((u16x4*)d)[j] = o;
    } else if (bx < 7168) {     // 4 x 1024x1024 fp32->bf16 transposes
        int r = bx - 6144;
        int z = r >> 8, xy = r & 255, tbx = xy & 15, tby = xy >> 4;
        const float* ip; US* op;
        switch (z) {
            case 0: ip = Rm; op = rt; break;
            case 1: ip = Em; op = et; break;
            case 2: ip = qkvw; op = wqT; break;
            default: ip = qkvw + (size_t)1024 * 1024; op = wkT; break;
        }
        int bc = tbx * 64, br = tby * 64;
        int lx = threadIdx.x & 63, y4 = threadIdx.x >> 6;
#pragma unroll
        for (int i = 0; i < 16; ++i) {
            int rr = i * 4 + y4;
            t[rr][lx] = ip[(size_t)(br + rr) * 1024 + bc + lx];
        }
        __syncthreads();
#pragma unroll
        for (int i = 0; i < 16; ++i) {
            int c = i * 4 + y4;
            op[(size_t)(bc + c) * 1024 + br + lx] = f2bf(t[lx][c]);
        }
    } else if (bx < 7296) {     // bias GEMV partials: 32 n-chunks x 4 j-chunks
        float (*red)[64] = (float(*)[64])t;
        const int bb = bx - 7168;
        const int tid = threadIdx.x, wave = tid >> 6, lane = tid & 63;
        const int nc = bb & 31, jc = bb >> 5;
        const int n0 = nc * 64, n = n0 + lane;
        const float* M = (n0 < 1024) ? Rm : Em;
        const float* bv = qkvb + ((n0 < 1024) ? 0 : 1024);
        const int nn = (n0 < 1024) ? n : n - 1024;
        float s = 0.f;
        const int j0 = jc * 256 + wave * 64;
#pragma unroll 8
        for (int j = 0; j < 64; ++j)
            s += bv[j0 + j] * M[(size_t)(j0 + j) * 1024 + nn];
        red[wave][lane] = s;
        __syncthreads();
        if (wave == 0) {
            float tt = red[0][lane] + red[1][lane] + red[2][lane] + red[3][lane];
            atomicAdd(&b3[n], (n0 < 1024) ? tt * ALPHA_Q : tt);
        }
    } else {                    // v-bias copy
        int i = (bx - 7296) * 256 + threadIdx.x;
        b3[2048 + i] = qkvb[2048 + i];
    }
}

// ---------------------------------------------------------------------------
// NT GEMM, 64x128 tile (higher TLP for short-K shapes): C = A.B^T (+bias)
// (+resid). Grid (M/64, N/128); 256 thr / 4 waves; wave tile 32x64.
// ---------------------------------------------------------------------------
template <typename TO>
__global__ __launch_bounds__(256) void gemm_nt64(
    const US* __restrict__ A, const US* __restrict__ Bm,
    TO* __restrict__ C, const float* __restrict__ bias,
    const float* __restrict__ resid,
    int M, int N, int K, int lda, int ldb, int ldc)
{
    __shared__ __align__(16) US sA[64 * 32];
    __shared__ __align__(16) US sB[128 * 32];
    const int tid = threadIdx.x;
    const int wave = tid >> 6, lane = tid & 63;
    const int r16 = lane & 15, q4 = lane >> 4;
    const int wm = (wave >> 1) * 32, wn = (wave & 1) * 64;

    const US* aptr = A + (size_t)(blockIdx.x * 64 + wave * 16 + (lane >> 2)) * lda + (lane & 3) * 8;
    const US* bptr = Bm + (size_t)(blockIdx.y * 128 + wave * 32 + (lane >> 2)) * ldb + (lane & 3) * 8;
    US* lA = sA + (wave * 16) * 32;
    US* lB = sB + (wave * 32) * 32;

    f32x4 acc[2][4];
#pragma unroll
    for (int i = 0; i < 2; ++i)
#pragma unroll
        for (int j = 0; j < 4; ++j) acc[i][j] = (f32x4){0.f, 0.f, 0.f, 0.f};

    for (int k0 = 0; k0 < K; k0 += 32) {
        gload16(aptr + k0, lA);
        gload16(bptr + k0, lB);
        gload16(bptr + (size_t)16 * ldb + k0, lB + 16 * 32);
        __syncthreads();
        bf16x8 af[2], bfr[4];
#pragma unroll
        for (int i = 0; i < 2; ++i)
            af[i] = *(const bf16x8*)&sA[(wm + i * 16 + r16) * 32 + q4 * 8];
#pragma unroll
        for (int j = 0; j < 4; ++j)
            bfr[j] = *(const bf16x8*)&sB[(wn + j * 16 + r16) * 32 + q4 * 8];
#pragma unroll
        for (int i = 0; i < 2; ++i)
#pragma unroll
            for (int j = 0; j < 4; ++j) acc[i][j] = mfma16(af[i], bfr[j], acc[i][j]);
        __syncthreads();
    }

#pragma unroll
    for (int j = 0; j < 4; ++j) {
        int col = blockIdx.y * 128 + wn + j * 16 + r16;
        float bv = bias ? bias[col] : 0.f;
#pragma unroll
        for (int i = 0; i < 2; ++i) {
#pragma unroll
            for (int rr = 0; rr < 4; ++rr) {
                int row = blockIdx.x * 64 + wm + i * 16 + q4 * 4 + rr;
                float v = acc[i][j][rr] + bv;
                if (resid) v += resid[(size_t)row * ldc + col];
                stf(&C[(size_t)row * ldc + col], v);
            }
        }
    }
}

// ---------------------------------------------------------------------------
// qkv GEMM, 64x128 tiles, split epilogue: cols [0,2048) -> bf16 qk buffer;
// cols [2048,3072) -> V fp8, transposed into vt[b][feat][2048] with keys
// interleaved per 64-block: pos = [q4(2b)][ks(1b)][j(3b)] so one b128 LDS
// read in attention yields both 8-key MFMA fragments. Grid (64, 24).
// ---------------------------------------------------------------------------
__global__ __launch_bounds__(256) void gemm_qkv(
    const US* __restrict__ A, const US* __restrict__ Bm,
    const float* __restrict__ bias,
    US* __restrict__ qk, UC* __restrict__ vt)
{
    __shared__ __align__(16) US sA[64 * 32];
    __shared__ __align__(16) US sB[128 * 32];
    const int tid = threadIdx.x;
    const int wave = tid >> 6, lane = tid & 63;
    const int r16 = lane & 15, q4 = lane >> 4;
    const int wm = (wave >> 1) * 32, wn = (wave & 1) * 64;

    const US* aptr = A + (size_t)(blockIdx.x * 64 + wave * 16 + (lane >> 2)) * 1024 + (lane & 3) * 8;
    const US* bptr = Bm + (size_t)(blockIdx.y * 128 + wave * 32 + (lane >> 2)) * 1024 + (lane & 3) * 8;
    US* lA = sA + (wave * 16) * 32;
    US* lB = sB + (wave * 32) * 32;

    f32x4 acc[2][4];
#pragma unroll
    for (int i = 0; i < 2; ++i)
#pragma unroll
        for (int j = 0; j < 4; ++j) acc[i][j] = (f32x4){0.f, 0.f, 0.f, 0.f};

    for (int k0 = 0; k0 < 1024; k0 += 32) {
        gload16(aptr + k0, lA);
        gload16(bptr + k0, lB);
        gload16(bptr + (size_t)16 * 1024 + k0, lB + 16 * 32);
        __syncthreads();
        bf16x8 af[2], bfr[4];
#pragma unroll
        for (int i = 0; i < 2; ++i)
            af[i] = *(const bf16x8*)&sA[(wm + i * 16 + r16) * 32 + q4 * 8];
#pragma unroll
        for (int j = 0; j < 4; ++j)
            bfr[j] = *(const bf16x8*)&sB[(wn + j * 16 + r16) * 32 + q4 * 8];
#pragma unroll
        for (int i = 0; i < 2; ++i)
#pragma unroll
            for (int j = 0; j < 4; ++j) acc[i][j] = mfma16(af[i], bfr[j], acc[i][j]);
        __syncthreads();
    }

    if (blockIdx.y < 16) {          // q' | k' -> bf16 row-major [4096][2048]
#pragma unroll
        for (int j = 0; j < 4; ++j) {
            int col = blockIdx.y * 128 + wn + j * 16 + r16;
            float bv = bias[col];
#pragma unroll
            for (int i = 0; i < 2; ++i)
#pragma unroll
                for (int rr = 0; rr < 4; ++rr) {
                    int row = blockIdx.x * 64 + wm + i * 16 + q4 * 4 + rr;
                    qk[(size_t)row * 2048 + col] = f2bf(acc[i][j][rr] + bv);
                }
        }
    } else {                        // v -> fp8, transposed + key-interleaved
#pragma unroll
        for (int j = 0; j < 4; ++j) {
            int col = blockIdx.y * 128 + wn + j * 16 + r16;
            float bv = bias[col];
            int f = col - 2048;
#pragma unroll
            for (int i = 0; i < 2; ++i) {
                int row0 = blockIdx.x * 64 + wm + i * 16 + q4 * 4;
                int b = row0 >> 11, s0 = row0 & 2047;
                int k = s0 & 63;
                int p = (s0 & ~63) | ((k & 24) << 1) | ((k & 32) >> 2) | (k & 7);
                int dw = __builtin_amdgcn_cvt_pk_fp8_f32(
                    acc[i][j][0] + bv, acc[i][j][1] + bv, 0, false);
                dw = __builtin_amdgcn_cvt_pk_fp8_f32(
                    acc[i][j][2] + bv, acc[i][j][3] + bv, dw, true);
                *(unsigned int*)&vt[((size_t)(b * 1024 + f)) * 2048 + p] = (unsigned)dw;
            }
        }
    }
}

// ---------------------------------------------------------------------------
// Weight-fold GEMMs, 64x64 tiles, both folds in one launch (z: 0=q, 1=k).
// ---------------------------------------------------------------------------
__global__ __launch_bounds__(256) void gemm_fold(
    const US* __restrict__ rt, const US* __restrict__ wqT,
    const US* __restrict__ et, const US* __restrict__ wkT,
    US* __restrict__ comb)
{
    __shared__ __align__(16) US sA[64 * 32];
    __shared__ __align__(16) US sB[64 * 32];
    const US* A; const US* Bm; US* C; float alpha;
    if (blockIdx.z == 0) { A = rt; Bm = wqT; C = comb; alpha = ALPHA_Q; }
    else { A = et; Bm = wkT; C = comb + (size_t)1024 * 1024; alpha = 1.0f; }

    const int tid = threadIdx.x;
    const int wave = tid >> 6, lane = tid & 63;
    const int r16 = lane & 15, q4 = lane >> 4;
    const int wm = (wave >> 1) * 32, wn = (wave & 1) * 32;

    const int srow = wave * 16 + (lane >> 2);
    const int sg = lane & 3;
    const US* aptr = A + (size_t)(blockIdx.x * 64 + srow) * 1024 + sg * 8;
    const US* bptr = Bm + (size_t)(blockIdx.y * 64 + srow) * 1024 + sg * 8;
    US* lA = sA + (wave * 16) * 32;
    US* lB = sB + (wave * 16) * 32;

    f32x4 acc[2][2];
#pragma unroll
    for (int i = 0; i < 2; ++i)
#pragma unroll
        for (int j = 0; j < 2; ++j) acc[i][j] = (f32x4){0.f, 0.f, 0.f, 0.f};

    for (int k0 = 0; k0 < 1024; k0 += 32) {
        gload16(aptr + k0, lA);
        gload16(bptr + k0, lB);
        __syncthreads();
        bf16x8 af[2], bfr[2];
#pragma unroll
        for (int i = 0; i < 2; ++i)
            af[i] = *(const bf16x8*)&sA[(wm + i * 16 + r16) * 32 + q4 * 8];
#pragma unroll
        for (int j = 0; j < 2; ++j)
            bfr[j] = *(const bf16x8*)&sB[(wn + j * 16 + r16) * 32 + q4 * 8];
#pragma unroll
        for (int i = 0; i < 2; ++i)
#pragma unroll
            for (int j = 0; j < 2; ++j) acc[i][j] = mfma16(af[i], bfr[j], acc[i][j]);
        __syncthreads();
    }

#pragma unroll
    for (int j = 0; j < 2; ++j) {
        int col = blockIdx.y * 64 + wn + j * 16 + r16;
#pragma unroll
        for (int i = 0; i < 2; ++i)
#pragma unroll
            for (int rr = 0; rr < 4; ++rr) {
                int row = blockIdx.x * 64 + wm + i * 16 + q4 * 4 + rr;
                C[(size_t)row * 1024 + col] = f2bf(acc[i][j][rr] * alpha);
            }
    }
}

// ---------------------------------------------------------------------------
// Flash attention, wave-cooperative. B=2 H=16 S=2048 D=64; scores pre-scaled
// (log2 domain). Block = 4 waves sharing 64 q-rows of one (b,h); 64-key K/V
// tiles (dbuf) staged by all waves. Phase 1: wave w computes the 16-key
// slice [w*16,w*16+16) of S^T = K.Q^T, exp2 -> fp8 P -> shared LDS.
// Phase 2: wave w computes its 16-d slice of O^T += V^T.P^T (fp8 MFMA)
// reading the full cross-wave P. 2 raw s_barriers/iter + per-wave vmcnt.
// Grid 1024 = 4 blocks/CU = 16 waves/CU. XCD swizzle: 4 pairs/XCD.
// ---------------------------------------------------------------------------
__global__ __launch_bounds__(256) void attn_kernel(
    const US* __restrict__ qk, const UC* __restrict__ vt, US* __restrict__ out)
{
    __shared__ __align__(16) US sK[2 * 64 * 64];   // bf16 [buf][key][d]  16 KB
    __shared__ __align__(16) UC sV[2 * 64 * 64];   // fp8  [buf][d][key-ilv] 8 KB
    __shared__ __align__(16) UC sP[64 * 72];       // fp8  [q][key] (+8 pad) 4.5 KB
    __shared__ float lred[4][64];
    const int tid = threadIdx.x;
    const int wave = tid >> 6, lane = tid & 63;
    const int r16 = lane & 15, q4 = lane >> 4;
    const int bid = blockIdx.x;                    // 1024 blocks
    const int pair = (bid & 7) * 4 + ((bid >> 3) & 3);
    const int qc = bid >> 5;                       // 0..31
    const int h = pair & 15, b = pair >> 4;
    const int qrow0 = qc * 64;
    const int c7 = r16 & 7;

    // Q B-frags [n=q][k=d] for ALL 64 block q-rows (each wave holds a copy)
    const US* qbase = qk + ((size_t)(b * 2048 + qrow0)) * 2048 + h * 64;
    bf16x8 qa[4][2];
#pragma unroll
    for (int qt = 0; qt < 4; ++qt)
#pragma unroll
        for (int kh = 0; kh < 2; ++kh)
            qa[qt][kh] = *(const bf16x8*)(qbase + (size_t)(qt * 16 + r16) * 2048 + kh * 32 + q4 * 8);

    f32x4 o[4];          // O^T slice: [d = wave*16 + q4*4+rr][q = qt*16+r16]
    float lacc[4];       // per-qt partial denominators (this wave's keys only)
#pragma unroll
    for (int qt = 0; qt < 4; ++qt) { o[qt] = (f32x4){0.f, 0.f, 0.f, 0.f}; lacc[qt] = 0.f; }

    // staging lane constants (XOR granule swizzle baked into source address)
    const int l8 = lane >> 3;
    const US* kg = qk + ((size_t)(b * 2048 + wave * 16 + l8)) * 2048 + 1024 + h * 64
                 + ((lane & 7) ^ l8) * 8;
    const int r4 = lane >> 2;
    const UC* vg = vt + ((size_t)((b * 16 + h) * 64 + wave * 16 + r4)) * 2048
                 + ((lane & 3) ^ (r4 & 3)) * 16;

#define STAGE(kc, buf) do {                                                    \
        US* dK = sK + (buf) * 4096 + (wave * 16) * 64;                         \
        UC* dV = sV + (buf) * 4096 + (wave * 16) * 64;                         \
        gload16(kg + (size_t)(kc) * 2048, dK);                                 \
        gload16(kg + (size_t)((kc) + 8) * 2048, dK + 8 * 64);                  \
        gload16b(vg + (kc), dV);                                               \
    } while (0)

    STAGE(0, 0);
    for (int it = 0; it < 32; ++it) {
        const int buf = it & 1;
        asm volatile("s_waitcnt vmcnt(0)" ::: "memory");   // my part of tile `it`
        asm volatile("s_barrier" ::: "memory");            // everyone's part; PV(it-1) done
        if (it < 31) STAGE((it + 1) * 64, buf ^ 1);

        // phase 1: S^T slice = K_slice . Q^T ; P = exp2 -> fp8 -> shared LDS
        const US* K0 = sK + buf * 4096;
        bf16x8 kf0 = *(const bf16x8*)&K0[(wave * 16 + r16) * 64 + ((0 + q4) ^ c7) * 8];
        bf16x8 kf1 = *(const bf16x8*)&K0[(wave * 16 + r16) * 64 + ((4 + q4) ^ c7) * 8];
#pragma unroll
        for (int qt = 0; qt < 4; ++qt) {
            f32x4 st = mfma16(kf0, qa[qt][0], (f32x4){0.f, 0.f, 0.f, 0.f});
            st = mfma16(kf1, qa[qt][1], st);
            float p0 = EXP2F(st[0]), p1 = EXP2F(st[1]);
            float p2 = EXP2F(st[2]), p3 = EXP2F(st[3]);
            lacc[qt] += (p0 + p1) + (p2 + p3);
            int dw = __builtin_amdgcn_cvt_pk_fp8_f32(p0, p1, 0, false);
            dw = __builtin_amdgcn_cvt_pk_fp8_f32(p2, p3, dw, true);
            // P[q = qt*16+r16][key = wave*16 + q4*4 + rr] (b32, <=2-way banks)
            *(unsigned int*)&sP[(qt * 16 + r16) * 72 + wave * 16 + q4 * 4] = (unsigned)dw;
        }
        asm volatile("s_waitcnt lgkmcnt(0)" ::: "memory");
        asm volatile("s_barrier" ::: "memory");            // P visible to all waves

        // phase 2: O^T slice (d = wave*16..+16) += V^T_slice . P^T (fp8)
        const UC* V0 = sV + buf * 4096;
        u32x4 vv = *(const u32x4*)&V0[(wave * 16 + r16) * 64 + (q4 ^ (r16 & 3)) * 16];
        long long vf0, vf1;
        { uint2v t0 = {vv.x, vv.y}; vf0 = *(long long*)&t0; }
        { uint2v t1 = {vv.z, vv.w}; vf1 = *(long long*)&t1; }
#pragma unroll
        for (int qt = 0; qt < 4; ++qt) {
            long long pa0 = *(const long long*)&sP[(qt * 16 + r16) * 72 + q4 * 8];
            long long pa1 = *(const long long*)&sP[(qt * 16 + r16) * 72 + 32 + q4 * 8];
            o[qt] = mfma_fp8(vf0, pa0, o[qt]);
            o[qt] = mfma_fp8(vf1, pa1, o[qt]);
        }
    }
#undef STAGE

    // epilogue: combine l across quads (this wave) then across waves (LDS)
#pragma unroll
    for (int qt = 0; qt < 4; ++qt) {
        float l = lacc[qt];
        l += __shfl_xor(l, 16);
        l += __shfl_xor(l, 32);
        if (q4 == 0) lred[wave][qt * 16 + r16] = l;
    }
    __syncthreads();
#pragma unroll
    for (int qt = 0; qt < 4; ++qt) {
        int i = qt * 16 + r16;
        float l = lred[0][i] + lred[1][i] + lred[2][i] + lred[3][i];
        float inv = 1.0f / l;
        size_t row = (size_t)(b * 2048 + qrow0 + qt * 16 + r16);
        uint2v w;
        w.x = (unsigned)f2bf(o[qt][0] * inv) | ((unsigned)f2bf(o[qt][1] * inv) << 16);
        w.y = (unsigned)f2bf(o[qt][2] * inv) | ((unsigned)f2bf(o[qt][3] * inv) << 16);
        *(uint2v*)&out[row * 1024 + h * 64 + wave * 16 + q4 * 4] = w;
    }
}

// ---------------------------------------------------------------------------
// B=2, S=2048, E=1024, H=16, D=64. Inputs fp32, output fp32. 5 kernels.
// ---------------------------------------------------------------------------
extern "C" void kernel_launch(void* const* d_in, const int* in_sizes, int n_in,
                              void* d_out, int out_size, void* d_ws, size_t ws_size,
                              hipStream_t stream)
{
    const float* x    = (const float*)d_in[0];
    const float* Rm   = (const float*)d_in[1];
    const float* Em   = (const float*)d_in[2];
    const float* qkvw = (const float*)d_in[3];
    const float* qkvb = (const float*)d_in[4];
    const float* outw = (const float*)d_in[5];
    const float* outb = (const float*)d_in[6];
    float* outp = (float*)d_out;

    US* ws    = (US*)d_ws;
    US* xb    = ws;
    US* rt    = xb   + (size_t)4096 * 1024;
    US* et    = rt   + (size_t)1024 * 1024;
    US* wqT   = et   + (size_t)1024 * 1024;
    US* wkT   = wqT  + (size_t)1024 * 1024;
    US* wo    = wkT  + (size_t)1024 * 1024;
    US* comb  = wo   + (size_t)1024 * 1024;   // 3072 x 1024 fused weight
    US* qkvq  = comb + (size_t)3072 * 1024;   // 4096 x 2048: q' | k' (bf16)
    US* ao    = qkvq + (size_t)4096 * 2048;
    UC* vt    = (UC*)(ao + (size_t)4096 * 1024);   // fp8 [b][feat][s-ilv], 4 MB
    float* b3 = (float*)(vt + (size_t)2048 * 2048);

    // zero the accumulated bias region (atomicAdd targets)
    hipMemsetAsync(b3, 0, 2048 * sizeof(float), stream);
    // casts + 4 transposes + bias-GEMV partials + v-bias in one launch
    prep<<<dim3(7300), dim3(256), 0, stream>>>(
        x, xb, qkvw, comb + (size_t)2048 * 1024, outw, wo,
        Rm, rt, Em, et, wqT, wkT, qkvb, b3);
    // comb_q = ALPHA_Q * R^T Wq ; comb_k = E^T Wk
    gemm_fold<<<dim3(16, 16, 2), dim3(256), 0, stream>>>(rt, wqT, et, wkT, comb);
    // qkv: q'|k' -> qkvq (bf16), v -> vt (fp8, transposed+interleaved)
    gemm_qkv<<<dim3(64, 24), dim3(256), 0, stream>>>(xb, comb, b3, qkvq, vt);
    // attention (wave-cooperative)
    attn_kernel<<<dim3(1024), dim3(256), 0, stream>>>(qkvq, vt, ao);
    // out = ao @ out_w^T + out_b + x
    gemm_nt64<float><<<dim3(64, 8), dim3(256), 0, stream>>>(ao, wo, outp, outb, x,
                                                            4096, 1024, 1024, 1024, 1024, 1024);
}

// Round 9
// 212.545 us; speedup vs baseline: 1.4346x; 1.0926x over previous
//
#include <hip/hip_runtime.h>

#define US unsigned short
#define UC unsigned char

typedef __bf16 bf16x8 __attribute__((ext_vector_type(8)));
typedef float f32x4 __attribute__((ext_vector_type(4)));
typedef unsigned int u32x4 __attribute__((ext_vector_type(4)));
typedef unsigned short u16x4 __attribute__((ext_vector_type(4)));
typedef unsigned int uint2v __attribute__((ext_vector_type(2)));

// 0.125 (softmax 1/sqrt(D)) * log2(e): folded into W'q and b'q -> P = exp2(s).
#define ALPHA_Q 0.180336880111f

#if __has_builtin(__builtin_amdgcn_exp2f)
#define EXP2F(x) __builtin_amdgcn_exp2f(x)
#else
#define EXP2F(x) __expf(0.69314718f * (x))
#endif

static __device__ __forceinline__ US f2bf(float f) {  // RTNE
    union { float f; unsigned u; } v; v.f = f;
    unsigned r = v.u + 0x7fffu + ((v.u >> 16) & 1u);
    return (US)(r >> 16);
}
static __device__ __forceinline__ float bf2f(US h) {
    union { unsigned u; float f; } v; v.u = ((unsigned)h) << 16;
    return v.f;
}
static __device__ __forceinline__ f32x4 mfma16(bf16x8 a, bf16x8 b, f32x4 c) {
    return __builtin_amdgcn_mfma_f32_16x16x32_bf16(a, b, c, 0, 0, 0);
}
static __device__ __forceinline__ f32x4 mfma_fp8(long long a, long long b, f32x4 c) {
    return __builtin_amdgcn_mfma_f32_16x16x32_fp8_fp8(a, b, c, 0, 0, 0);
}
// async global->LDS, 16B/lane; LDS dest = base + lane*16 (wave-uniform base)
static __device__ __forceinline__ void gload16(const US* g, US* l) {
    __builtin_amdgcn_global_load_lds(
        (const __attribute__((address_space(1))) void*)g,
        (__attribute__((address_space(3))) void*)l, 16, 0, 0);
}
static __device__ __forceinline__ void gload16b(const UC* g, UC* l) {
    __builtin_amdgcn_global_load_lds(
        (const __attribute__((address_space(1))) void*)g,
        (__attribute__((address_space(3))) void*)l, 16, 0, 0);
}
static __device__ __forceinline__ void stf(float* p, float v) { *p = v; }
static __device__ __forceinline__ void stf(US* p, float v) { *p = f2bf(v); }

// ---------------------------------------------------------------------------
// Fused prep: [0,6144) f32->bf16 casts; [6144,7168) 4 transposes;
// [7168,7296) bias-GEMV partials (atomicAdd into pre-zeroed b3);
// [7296,7300) v-bias copy.
// ---------------------------------------------------------------------------
__global__ __launch_bounds__(256) void prep(
    const float* __restrict__ x, US* __restrict__ xb,
    const float* __restrict__ qkvw, US* __restrict__ wv,
    const float* __restrict__ outw, US* __restrict__ wo,
    const float* __restrict__ Rm, US* __restrict__ rt,
    const float* __restrict__ Em, US* __restrict__ et,
    US* __restrict__ wqT, US* __restrict__ wkT,
    const float* __restrict__ qkvb, float* __restrict__ b3)
{
    __shared__ float t[64][65];
    const int bx = blockIdx.x;
    if (bx < 6144) {            // bulk casts: x (4096 blks), Wv (1024), Wo (1024)
        int i = bx * 256 + threadIdx.x;
        const float* s; US* d; int j;
        if (i < 1048576) { s = x; d = xb; j = i; }
        else if (i < 1310720) { s = qkvw + (size_t)2048 * 1024; d = wv; j = i - 1048576; }
        else { s = outw; d = wo; j = i - 1310720; }
        f32x4 v = ((const f32x4*)s)[j];
        u16x4 o;
        o.x = f2bf(v.x); o.y = f2bf(v.y); o.z = f2bf(v.z); o.w = f2bf(v.w);
        ((u16x4*)d)[j] = o;
    } else if (bx < 7168) {     // 4 x 1024x1024 fp32->bf16 transposes
        int r = bx - 6144;
        int z = r >> 8, xy = r & 255, tbx = xy & 15, tby = xy >> 4;
        const float* ip; US* op;
        switch (z) {
            case 0: ip = Rm; op = rt; break;
            case 1: ip = Em; op = et; break;
            case 2: ip = qkvw; op = wqT; break;
            default: ip = qkvw + (size_t)1024 * 1024; op = wkT; break;
        }
        int bc = tbx * 64, br = tby * 64;
        int lx = threadIdx.x & 63, y4 = threadIdx.x >> 6;
#pragma unroll
        for (int i = 0; i < 16; ++i) {
            int rr = i * 4 + y4;
            t[rr][lx] = ip[(size_t)(br + rr) * 1024 + bc + lx];
        }
        __syncthreads();
#pragma unroll
        for (int i = 0; i < 16; ++i) {
            int c = i * 4 + y4;
            op[(size_t)(bc + c) * 1024 + br + lx] = f2bf(t[lx][c]);
        }
    } else if (bx < 7296) {     // bias GEMV partials: 32 n-chunks x 4 j-chunks
        float (*red)[64] = (float(*)[64])t;
        const int bb = bx - 7168;
        const int tid = threadIdx.x, wave = tid >> 6, lane = tid & 63;
        const int nc = bb & 31, jc = bb >> 5;
        const int n0 = nc * 64, n = n0 + lane;
        const float* M = (n0 < 1024) ? Rm : Em;
        const float* bv = qkvb + ((n0 < 1024) ? 0 : 1024);
        const int nn = (n0 < 1024) ? n : n - 1024;
        float s = 0.f;
        const int j0 = jc * 256 + wave * 64;
#pragma unroll 8
        for (int j = 0; j < 64; ++j)
            s += bv[j0 + j] * M[(size_t)(j0 + j) * 1024 + nn];
        red[wave][lane] = s;
        __syncthreads();
        if (wave == 0) {
            float tt = red[0][lane] + red[1][lane] + red[2][lane] + red[3][lane];
            atomicAdd(&b3[n], (n0 < 1024) ? tt * ALPHA_Q : tt);
        }
    } else {                    // v-bias copy
        int i = (bx - 7296) * 256 + threadIdx.x;
        b3[2048 + i] = qkvb[2048 + i];
    }
}

// ---------------------------------------------------------------------------
// NT GEMM, 64x128 tile, BK=64 (halved barrier count): C = A.B^T (+bias)
// (+resid). 128B LDS rows with XOR granule swizzle (conflict-free b128).
// Grid (M/64, N/128); 4 waves; wave tile 32x64.
// ---------------------------------------------------------------------------
template <typename TO>
__global__ __launch_bounds__(256) void gemm_nt64(
    const US* __restrict__ A, const US* __restrict__ Bm,
    TO* __restrict__ C, const float* __restrict__ bias,
    const float* __restrict__ resid,
    int M, int N, int K, int lda, int ldb, int ldc)
{
    __shared__ __align__(16) US sA[64 * 64];    //  8 KB
    __shared__ __align__(16) US sB[128 * 64];   // 16 KB
    const int tid = threadIdx.x;
    const int wave = tid >> 6, lane = tid & 63;
    const int r16 = lane & 15, q4 = lane >> 4;
    const int wm = (wave >> 1) * 32, wn = (wave & 1) * 64;
    const int c7 = r16 & 7;

    const int l8 = lane >> 3, lg = (lane & 7) ^ l8;   // XOR baked into source
    const US* aptr = A + (size_t)(blockIdx.x * 64 + wave * 16 + l8) * lda + lg * 8;
    const US* bptr = Bm + (size_t)(blockIdx.y * 128 + wave * 32 + l8) * ldb + lg * 8;

    f32x4 acc[2][4];
#pragma unroll
    for (int i = 0; i < 2; ++i)
#pragma unroll
        for (int j = 0; j < 4; ++j) acc[i][j] = (f32x4){0.f, 0.f, 0.f, 0.f};

    for (int k0 = 0; k0 < K; k0 += 64) {
        gload16(aptr + k0, sA + (wave * 16) * 64);
        gload16(aptr + (size_t)8 * lda + k0, sA + (wave * 16 + 8) * 64);
#pragma unroll
        for (int c = 0; c < 4; ++c)
            gload16(bptr + (size_t)(c * 8) * ldb + k0, sB + (wave * 32 + c * 8) * 64);
        __syncthreads();
        bf16x8 af[2][2], bfr[4][2];
#pragma unroll
        for (int i = 0; i < 2; ++i)
#pragma unroll
            for (int hf = 0; hf < 2; ++hf)
                af[i][hf] = *(const bf16x8*)&sA[(wm + i * 16 + r16) * 64 + ((hf * 4 + q4) ^ c7) * 8];
#pragma unroll
        for (int j = 0; j < 4; ++j)
#pragma unroll
            for (int hf = 0; hf < 2; ++hf)
                bfr[j][hf] = *(const bf16x8*)&sB[(wn + j * 16 + r16) * 64 + ((hf * 4 + q4) ^ c7) * 8];
#pragma unroll
        for (int i = 0; i < 2; ++i)
#pragma unroll
            for (int j = 0; j < 4; ++j) {
                acc[i][j] = mfma16(af[i][0], bfr[j][0], acc[i][j]);
                acc[i][j] = mfma16(af[i][1], bfr[j][1], acc[i][j]);
            }
        __syncthreads();
    }

#pragma unroll
    for (int j = 0; j < 4; ++j) {
        int col = blockIdx.y * 128 + wn + j * 16 + r16;
        float bv = bias ? bias[col] : 0.f;
#pragma unroll
        for (int i = 0; i < 2; ++i) {
#pragma unroll
            for (int rr = 0; rr < 4; ++rr) {
                int row = blockIdx.x * 64 + wm + i * 16 + q4 * 4 + rr;
                float v = acc[i][j][rr] + bv;
                if (resid) v += resid[(size_t)row * ldc + col];
                stf(&C[(size_t)row * ldc + col], v);
            }
        }
    }
}

// ---------------------------------------------------------------------------
// qkv GEMM, 64x128 tile, BK=64, split epilogue: cols [0,2048) -> bf16 qk;
// cols [2048,3072) -> V fp8, transposed + key-interleaved into vt. Grid (64,24).
// ---------------------------------------------------------------------------
__global__ __launch_bounds__(256) void gemm_qkv(
    const US* __restrict__ A, const US* __restrict__ Bm,
    const float* __restrict__ bias,
    US* __restrict__ qk, UC* __restrict__ vt)
{
    __shared__ __align__(16) US sA[64 * 64];
    __shared__ __align__(16) US sB[128 * 64];
    const int tid = threadIdx.x;
    const int wave = tid >> 6, lane = tid & 63;
    const int r16 = lane & 15, q4 = lane >> 4;
    const int wm = (wave >> 1) * 32, wn = (wave & 1) * 64;
    const int c7 = r16 & 7;

    const int l8 = lane >> 3, lg = (lane & 7) ^ l8;
    const US* aptr = A + (size_t)(blockIdx.x * 64 + wave * 16 + l8) * 1024 + lg * 8;
    const US* bptr = Bm + (size_t)(blockIdx.y * 128 + wave * 32 + l8) * 1024 + lg * 8;

    f32x4 acc[2][4];
#pragma unroll
    for (int i = 0; i < 2; ++i)
#pragma unroll
        for (int j = 0; j < 4; ++j) acc[i][j] = (f32x4){0.f, 0.f, 0.f, 0.f};

    for (int k0 = 0; k0 < 1024; k0 += 64) {
        gload16(aptr + k0, sA + (wave * 16) * 64);
        gload16(aptr + (size_t)8 * 1024 + k0, sA + (wave * 16 + 8) * 64);
#pragma unroll
        for (int c = 0; c < 4; ++c)
            gload16(bptr + (size_t)(c * 8) * 1024 + k0, sB + (wave * 32 + c * 8) * 64);
        __syncthreads();
        bf16x8 af[2][2], bfr[4][2];
#pragma unroll
        for (int i = 0; i < 2; ++i)
#pragma unroll
            for (int hf = 0; hf < 2; ++hf)
                af[i][hf] = *(const bf16x8*)&sA[(wm + i * 16 + r16) * 64 + ((hf * 4 + q4) ^ c7) * 8];
#pragma unroll
        for (int j = 0; j < 4; ++j)
#pragma unroll
            for (int hf = 0; hf < 2; ++hf)
                bfr[j][hf] = *(const bf16x8*)&sB[(wn + j * 16 + r16) * 64 + ((hf * 4 + q4) ^ c7) * 8];
#pragma unroll
        for (int i = 0; i < 2; ++i)
#pragma unroll
            for (int j = 0; j < 4; ++j) {
                acc[i][j] = mfma16(af[i][0], bfr[j][0], acc[i][j]);
                acc[i][j] = mfma16(af[i][1], bfr[j][1], acc[i][j]);
            }
        __syncthreads();
    }

    if (blockIdx.y < 16) {          // q' | k' -> bf16 row-major [4096][2048]
#pragma unroll
        for (int j = 0; j < 4; ++j) {
            int col = blockIdx.y * 128 + wn + j * 16 + r16;
            float bv = bias[col];
#pragma unroll
            for (int i = 0; i < 2; ++i)
#pragma unroll
                for (int rr = 0; rr < 4; ++rr) {
                    int row = blockIdx.x * 64 + wm + i * 16 + q4 * 4 + rr;
                    qk[(size_t)row * 2048 + col] = f2bf(acc[i][j][rr] + bv);
                }
        }
    } else {                        // v -> fp8, transposed + key-interleaved
#pragma unroll
        for (int j = 0; j < 4; ++j) {
            int col = blockIdx.y * 128 + wn + j * 16 + r16;
            float bv = bias[col];
            int f = col - 2048;
#pragma unroll
            for (int i = 0; i < 2; ++i) {
                int row0 = blockIdx.x * 64 + wm + i * 16 + q4 * 4;
                int b = row0 >> 11, s0 = row0 & 2047;
                int k = s0 & 63;
                int p = (s0 & ~63) | ((k & 24) << 1) | ((k & 32) >> 2) | (k & 7);
                int dw = __builtin_amdgcn_cvt_pk_fp8_f32(
                    acc[i][j][0] + bv, acc[i][j][1] + bv, 0, false);
                dw = __builtin_amdgcn_cvt_pk_fp8_f32(
                    acc[i][j][2] + bv, acc[i][j][3] + bv, dw, true);
                *(unsigned int*)&vt[((size_t)(b * 1024 + f)) * 2048 + p] = (unsigned)dw;
            }
        }
    }
}

// ---------------------------------------------------------------------------
// Weight-fold GEMMs, 64x64 tiles, both folds in one launch (z: 0=q, 1=k).
// ---------------------------------------------------------------------------
__global__ __launch_bounds__(256) void gemm_fold(
    const US* __restrict__ rt, const US* __restrict__ wqT,
    const US* __restrict__ et, const US* __restrict__ wkT,
    US* __restrict__ comb)
{
    __shared__ __align__(16) US sA[64 * 32];
    __shared__ __align__(16) US sB[64 * 32];
    const US* A; const US* Bm; US* C; float alpha;
    if (blockIdx.z == 0) { A = rt; Bm = wqT; C = comb; alpha = ALPHA_Q; }
    else { A = et; Bm = wkT; C = comb + (size_t)1024 * 1024; alpha = 1.0f; }

    const int tid = threadIdx.x;
    const int wave = tid >> 6, lane = tid & 63;
    const int r16 = lane & 15, q4 = lane >> 4;
    const int wm = (wave >> 1) * 32, wn = (wave & 1) * 32;

    const int srow = wave * 16 + (lane >> 2);
    const int sg = lane & 3;
    const US* aptr = A + (size_t)(blockIdx.x * 64 + srow) * 1024 + sg * 8;
    const US* bptr = Bm + (size_t)(blockIdx.y * 64 + srow) * 1024 + sg * 8;
    US* lA = sA + (wave * 16) * 32;
    US* lB = sB + (wave * 16) * 32;

    f32x4 acc[2][2];
#pragma unroll
    for (int i = 0; i < 2; ++i)
#pragma unroll
        for (int j = 0; j < 2; ++j) acc[i][j] = (f32x4){0.f, 0.f, 0.f, 0.f};

    for (int k0 = 0; k0 < 1024; k0 += 32) {
        gload16(aptr + k0, lA);
        gload16(bptr + k0, lB);
        __syncthreads();
        bf16x8 af[2], bfr[2];
#pragma unroll
        for (int i = 0; i < 2; ++i)
            af[i] = *(const bf16x8*)&sA[(wm + i * 16 + r16) * 32 + q4 * 8];
#pragma unroll
        for (int j = 0; j < 2; ++j)
            bfr[j] = *(const bf16x8*)&sB[(wn + j * 16 + r16) * 32 + q4 * 8];
#pragma unroll
        for (int i = 0; i < 2; ++i)
#pragma unroll
            for (int j = 0; j < 2; ++j) acc[i][j] = mfma16(af[i], bfr[j], acc[i][j]);
        __syncthreads();
    }

#pragma unroll
    for (int j = 0; j < 2; ++j) {
        int col = blockIdx.y * 64 + wn + j * 16 + r16;
#pragma unroll
        for (int i = 0; i < 2; ++i)
#pragma unroll
            for (int rr = 0; rr < 4; ++rr) {
                int row = blockIdx.x * 64 + wm + i * 16 + q4 * 4 + rr;
                C[(size_t)row * 1024 + col] = f2bf(acc[i][j][rr] * alpha);
            }
    }
}

// ---------------------------------------------------------------------------
// Flash attention, wave-cooperative. Block = 4 waves sharing 64 q-rows of one
// (b,h); 64-key K/V dbuf tiles. Phase 1: wave w computes 16-key slice of
// S^T = K.Q^T, exp2 -> fp8 P -> shared LDS. Phase 2: wave w computes its
// 16-d slice of O^T += V^T.P^T (fp8 MFMA) over full P, and its qt-slice of
// the denominator via an fp8 ones-MFMA (l = ones . P^T — no VALU adds).
// Grid 1024 = 4 blocks/CU. XCD swizzle: 4 (b,h) pairs per XCD.
// ---------------------------------------------------------------------------
__global__ __launch_bounds__(256) void attn_kernel(
    const US* __restrict__ qk, const UC* __restrict__ vt, US* __restrict__ out)
{
    __shared__ __align__(16) US sK[2 * 64 * 64];   // bf16 [buf][key][d]  16 KB
    __shared__ __align__(16) UC sV[2 * 64 * 64];   // fp8  [buf][d][key-ilv] 8 KB
    __shared__ __align__(16) UC sP[64 * 72];       // fp8  [q][key] (+8 pad) 4.5 KB
    __shared__ float lred[64];
    const int tid = threadIdx.x;
    const int wave = tid >> 6, lane = tid & 63;
    const int r16 = lane & 15, q4 = lane >> 4;
    const int bid = blockIdx.x;                    // 1024 blocks
    const int pair = (bid & 7) * 4 + ((bid >> 3) & 3);
    const int qc = bid >> 5;                       // 0..31
    const int h = pair & 15, b = pair >> 4;
    const int qrow0 = qc * 64;
    const int c7 = r16 & 7;
    const long long ones8 = 0x3838383838383838LL; // 1.0 in e4m3, x8

    // Q B-frags [n=q][k=d] for ALL 64 block q-rows (each wave holds a copy)
    const US* qbase = qk + ((size_t)(b * 2048 + qrow0)) * 2048 + h * 64;
    bf16x8 qa[4][2];
#pragma unroll
    for (int qt = 0; qt < 4; ++qt)
#pragma unroll
        for (int kh = 0; kh < 2; ++kh)
            qa[qt][kh] = *(const bf16x8*)(qbase + (size_t)(qt * 16 + r16) * 2048 + kh * 32 + q4 * 8);

    f32x4 o[4];          // O^T slice: [d = wave*16 + q4*4+rr][q = qt*16+r16]
    f32x4 lC;            // denominator acc for qt == wave (value at [0])
#pragma unroll
    for (int qt = 0; qt < 4; ++qt) o[qt] = (f32x4){0.f, 0.f, 0.f, 0.f};
    lC = (f32x4){0.f, 0.f, 0.f, 0.f};

    // staging lane constants (XOR granule swizzle baked into source address)
    const int l8 = lane >> 3;
    const US* kg = qk + ((size_t)(b * 2048 + wave * 16 + l8)) * 2048 + 1024 + h * 64
                 + ((lane & 7) ^ l8) * 8;
    const int r4 = lane >> 2;
    const UC* vg = vt + ((size_t)((b * 16 + h) * 64 + wave * 16 + r4)) * 2048
                 + ((lane & 3) ^ (r4 & 3)) * 16;

#define STAGE(kc, buf) do {                                                    \
        US* dK = sK + (buf) * 4096 + (wave * 16) * 64;                         \
        UC* dV = sV + (buf) * 4096 + (wave * 16) * 64;                         \
        gload16(kg + (size_t)(kc) * 2048, dK);                                 \
        gload16(kg + (size_t)((kc) + 8) * 2048, dK + 8 * 64);                  \
        gload16b(vg + (kc), dV);                                               \
    } while (0)

    STAGE(0, 0);
    for (int it = 0; it < 32; ++it) {
        const int buf = it & 1;
        asm volatile("s_waitcnt vmcnt(0)" ::: "memory");   // my part of tile `it`
        asm volatile("s_barrier" ::: "memory");            // everyone's part; PV(it-1) done
        if (it < 31) STAGE((it + 1) * 64, buf ^ 1);

        // phase 1: S^T slice = K_slice . Q^T ; P = exp2 -> fp8 -> shared LDS
        const US* K0 = sK + buf * 4096;
        bf16x8 kf0 = *(const bf16x8*)&K0[(wave * 16 + r16) * 64 + ((0 + q4) ^ c7) * 8];
        bf16x8 kf1 = *(const bf16x8*)&K0[(wave * 16 + r16) * 64 + ((4 + q4) ^ c7) * 8];
#pragma unroll
        for (int qt = 0; qt < 4; ++qt) {
            f32x4 st = mfma16(kf0, qa[qt][0], (f32x4){0.f, 0.f, 0.f, 0.f});
            st = mfma16(kf1, qa[qt][1], st);
            float p0 = EXP2F(st[0]), p1 = EXP2F(st[1]);
            float p2 = EXP2F(st[2]), p3 = EXP2F(st[3]);
            int dw = __builtin_amdgcn_cvt_pk_fp8_f32(p0, p1, 0, false);
            dw = __builtin_amdgcn_cvt_pk_fp8_f32(p2, p3, dw, true);
            // P[q = qt*16+r16][key = wave*16 + q4*4 + rr] (b32, <=2-way banks)
            *(unsigned int*)&sP[(qt * 16 + r16) * 72 + wave * 16 + q4 * 4] = (unsigned)dw;
        }
        asm volatile("s_waitcnt lgkmcnt(0)" ::: "memory");
        asm volatile("s_barrier" ::: "memory");            // P visible to all waves

        // phase 2: O^T slice (d = wave*16..+16) += V^T_slice . P^T (fp8)
        const UC* V0 = sV + buf * 4096;
        u32x4 vv = *(const u32x4*)&V0[(wave * 16 + r16) * 64 + (q4 ^ (r16 & 3)) * 16];
        long long vf0, vf1;
        { uint2v t0 = {vv.x, vv.y}; vf0 = *(long long*)&t0; }
        { uint2v t1 = {vv.z, vv.w}; vf1 = *(long long*)&t1; }
#pragma unroll
        for (int qt = 0; qt < 4; ++qt) {
            long long pa0 = *(const long long*)&sP[(qt * 16 + r16) * 72 + q4 * 8];
            long long pa1 = *(const long long*)&sP[(qt * 16 + r16) * 72 + 32 + q4 * 8];
            o[qt] = mfma_fp8(vf0, pa0, o[qt]);
            o[qt] = mfma_fp8(vf1, pa1, o[qt]);
        }
        // denominator for qt == wave via ones-MFMA (C cols = q, rows identical)
        {
            long long pl0 = *(const long long*)&sP[(wave * 16 + r16) * 72 + q4 * 8];
            long long pl1 = *(const long long*)&sP[(wave * 16 + r16) * 72 + 32 + q4 * 8];
            lC = mfma_fp8(ones8, pl0, lC);
            lC = mfma_fp8(ones8, pl1, lC);
        }
    }
#undef STAGE

    // epilogue: share l across waves, normalize, store
    if (q4 == 0) lred[wave * 16 + r16] = lC[0];
    __syncthreads();
#pragma unroll
    for (int qt = 0; qt < 4; ++qt) {
        float inv = 1.0f / lred[qt * 16 + r16];
        size_t row = (size_t)(b * 2048 + qrow0 + qt * 16 + r16);
        uint2v w;
        w.x = (unsigned)f2bf(o[qt][0] * inv) | ((unsigned)f2bf(o[qt][1] * inv) << 16);
        w.y = (unsigned)f2bf(o[qt][2] * inv) | ((unsigned)f2bf(o[qt][3] * inv) << 16);
        *(uint2v*)&out[row * 1024 + h * 64 + wave * 16 + q4 * 4] = w;
    }
}

// ---------------------------------------------------------------------------
// B=2, S=2048, E=1024, H=16, D=64. Inputs fp32, output fp32. 5 kernels.
// ---------------------------------------------------------------------------
extern "C" void kernel_launch(void* const* d_in, const int* in_sizes, int n_in,
                              void* d_out, int out_size, void* d_ws, size_t ws_size,
                              hipStream_t stream)
{
    const float* x    = (const float*)d_in[0];
    const float* Rm   = (const float*)d_in[1];
    const float* Em   = (const float*)d_in[2];
    const float* qkvw = (const float*)d_in[3];
    const float* qkvb = (const float*)d_in[4];
    const float* outw = (const float*)d_in[5];
    const float* outb = (const float*)d_in[6];
    float* outp = (float*)d_out;

    US* ws    = (US*)d_ws;
    US* xb    = ws;
    US* rt    = xb   + (size_t)4096 * 1024;
    US* et    = rt   + (size_t)1024 * 1024;
    US* wqT   = et   + (size_t)1024 * 1024;
    US* wkT   = wqT  + (size_t)1024 * 1024;
    US* wo    = wkT  + (size_t)1024 * 1024;
    US* comb  = wo   + (size_t)1024 * 1024;   // 3072 x 1024 fused weight
    US* qkvq  = comb + (size_t)3072 * 1024;   // 4096 x 2048: q' | k' (bf16)
    US* ao    = qkvq + (size_t)4096 * 2048;
    UC* vt    = (UC*)(ao + (size_t)4096 * 1024);   // fp8 [b][feat][s-ilv], 4 MB
    float* b3 = (float*)(vt + (size_t)2048 * 2048);

    // zero the accumulated bias region (atomicAdd targets)
    hipMemsetAsync(b3, 0, 2048 * sizeof(float), stream);
    // casts + 4 transposes + bias-GEMV partials + v-bias in one launch
    prep<<<dim3(7300), dim3(256), 0, stream>>>(
        x, xb, qkvw, comb + (size_t)2048 * 1024, outw, wo,
        Rm, rt, Em, et, wqT, wkT, qkvb, b3);
    // comb_q = ALPHA_Q * R^T Wq ; comb_k = E^T Wk
    gemm_fold<<<dim3(16, 16, 2), dim3(256), 0, stream>>>(rt, wqT, et, wkT, comb);
    // qkv: q'|k' -> qkvq (bf16), v -> vt (fp8, transposed+interleaved)
    gemm_qkv<<<dim3(64, 24), dim3(256), 0, stream>>>(xb, comb, b3, qkvq, vt);
    // attention (wave-cooperative, MFMA denominator)
    attn_kernel<<<dim3(1024), dim3(256), 0, stream>>>(qkvq, vt, ao);
    // out = ao @ out_w^T + out_b + x
    gemm_nt64<float><<<dim3(64, 8), dim3(256), 0, stream>>>(ao, wo, outp, outb, x,
                                                            4096, 1024, 1024, 1024, 1024, 1024);
}